// Round 1
// baseline (1568.024 us; speedup 1.0000x reference)
//
#include <hip/hip_runtime.h>
#include <hip/hip_bf16.h>

// Problem: CausalMultiHeadSelfAttention  B=2 S=2048 D_MODEL=1024 H=16 DH=64
// Inputs (fp32): x[2,2048,1024], wqkv[3072,1024], w_out[1024,1024],
//                cos[2048,32], sin[2048,32], token_positions[2048] (int32)
// Output fp32 [2,2048,1024].
// Pipeline: cast->bf16, QKV GEMM (bf16 MFMA), RoPE (fp32), flash attention
// (fp32 vector, k-split 2 waves/block), out GEMM (bf16 MFMA).

#define S_LEN 2048
#define DMODEL 1024
#define NH 16
#define DH 64
#define QKVN 3072
#define TOKS 4096

typedef __attribute__((ext_vector_type(4))) short short4v;
typedef __attribute__((ext_vector_type(8))) short short8v;
typedef __attribute__((ext_vector_type(4))) float floatx4;

__device__ __forceinline__ unsigned short f2bf(float f) {
  unsigned int u = __float_as_uint(f);
  u += 0x7FFFu + ((u >> 16) & 1u);          // round-to-nearest-even
  return (unsigned short)(u >> 16);
}

__device__ __forceinline__ void gload16(const void* g, void* l) {
  __builtin_amdgcn_global_load_lds((const __attribute__((address_space(1))) void*)g,
                                   (__attribute__((address_space(3))) void*)l,
                                   16, 0, 0);
}

// ---------------- fp32 -> bf16 cast (vector x4) ----------------
__global__ __launch_bounds__(256) void cast_bf16_k(const float* __restrict__ in,
                                                   unsigned short* __restrict__ out,
                                                   int n4) {
  int i = blockIdx.x * 256 + threadIdx.x;
  if (i >= n4) return;
  float4 v = reinterpret_cast<const float4*>(in)[i];
  ushort4 o;
  o.x = f2bf(v.x); o.y = f2bf(v.y); o.z = f2bf(v.z); o.w = f2bf(v.w);
  reinterpret_cast<ushort4*>(out)[i] = o;
}

// ---------------- RoPE in place on qkv fp32 ----------------
// qkv[tok][3072]; q pairs at 2p (p=0..511), k pairs at 1024+2p. v untouched.
__global__ __launch_bounds__(256) void rope_k(float* __restrict__ qkv,
                                              const float* __restrict__ cosp,
                                              const float* __restrict__ sinp,
                                              const int* __restrict__ tpos) {
  int idx = blockIdx.x * 256 + threadIdx.x;   // 0 .. 4194303
  int t = idx >> 10;                          // token 0..4095
  int r = idx & 1023;
  int s = t & (S_LEN - 1);
  int mat = r >> 9;                           // 0 = q, 1 = k
  int p = r & 511;                            // pair index within 1024 dims
  int i = p & 31;                             // freq index
  int tp = tpos[s];
  float c = cosp[tp * 32 + i];
  float sn = sinp[tp * 32 + i];
  float2* ptr = (float2*)(qkv + (size_t)t * QKVN + mat * DMODEL + 2 * p);
  float2 v = *ptr;
  float re = v.x * c - v.y * sn;
  float ro = v.x * sn + v.y * c;
  float2 w; w.x = re; w.y = ro;
  *ptr = w;
}

// ---------------- bf16 MFMA GEMM:  C[M,N] = A[M,K] * B[N,K]^T ----------------
// 128x128 tile, BK=32, 4 waves (2x2), 16 MFMA/wave/K-step, global_load_lds w=16.
__global__ __launch_bounds__(256) void gemm_bt_bf16(const unsigned short* __restrict__ A,
                                                    const unsigned short* __restrict__ Bm,
                                                    float* __restrict__ C,
                                                    int M, int N, int K) {
  __shared__ __align__(16) unsigned short As[128 * 32];
  __shared__ __align__(16) unsigned short Bs[128 * 32];
  const int tid = threadIdx.x;
  const int lane = tid & 63;
  const int w = tid >> 6;            // wave 0..3
  const int wm = w >> 1, wn = w & 1; // 2x2 wave grid, each wave 64x64
  const int l15 = lane & 15, l4 = lane >> 4;
  const int bm = blockIdx.y * 128, bn = blockIdx.x * 128;
  const int srow = lane >> 2;        // 0..15
  const int skc = (lane & 3) * 8;    // k element offset (16B chunks)

  floatx4 acc[4][4] = {};

  const short4v* As4 = (const short4v*)As;
  const short4v* Bs4 = (const short4v*)Bs;

  for (int k0 = 0; k0 < K; k0 += 32) {
    // stage A,B tiles: per wave 2 issues each, linear LDS = row-major [128][32]
#pragma unroll
    for (int j = 0; j < 2; ++j) {
      const unsigned short* ga = A + (size_t)(bm + j * 64 + w * 16 + srow) * K + k0 + skc;
      gload16(ga, &As[j * 2048 + w * 512]);
      const unsigned short* gb = Bm + (size_t)(bn + j * 64 + w * 16 + srow) * K + k0 + skc;
      gload16(gb, &Bs[j * 2048 + w * 512]);
    }
    asm volatile("s_waitcnt vmcnt(0)" ::: "memory");
    __syncthreads();

    short8v af[4], bfr[4];
#pragma unroll
    for (int f = 0; f < 4; ++f) {
      int ra = wm * 64 + f * 16 + l15;
      union { short4v h[2]; short8v v; } ua;
      ua.h[0] = As4[ra * 8 + l4];
      ua.h[1] = As4[ra * 8 + 4 + l4];
      af[f] = ua.v;
      int rb = wn * 64 + f * 16 + l15;
      union { short4v h[2]; short8v v; } ub;
      ub.h[0] = Bs4[rb * 8 + l4];
      ub.h[1] = Bs4[rb * 8 + 4 + l4];
      bfr[f] = ub.v;
    }
#pragma unroll
    for (int f = 0; f < 4; ++f)
#pragma unroll
      for (int g = 0; g < 4; ++g)
        acc[f][g] = __builtin_amdgcn_mfma_f32_16x16x32_bf16(af[f], bfr[g], acc[f][g], 0, 0, 0);
    __syncthreads();
  }

  // epilogue: C/D layout col=lane&15, row=(lane>>4)*4+reg  (m89-verified)
#pragma unroll
  for (int f = 0; f < 4; ++f) {
#pragma unroll
    for (int g = 0; g < 4; ++g) {
#pragma unroll
      for (int r = 0; r < 4; ++r) {
        int row = bm + wm * 64 + f * 16 + l4 * 4 + r;
        int col = bn + wn * 64 + g * 16 + l15;
        C[(size_t)row * N + col] = acc[f][g][r];
      }
    }
  }
}

// ---------------- fp32 flash attention, k-split (2 waves/block) ----------------
// Block = 128 threads = 2 waves, one q-tile of 64 rows (rows = qt*64+lane).
// Wave w handles k in [w*kn, (w+1)*kn), kn = 32*(qt+1). Flash-combine via LDS.
__global__ __launch_bounds__(128) void attn_fp32_ksplit(const float* __restrict__ qkv,
                                                        unsigned short* __restrict__ y) {
  __shared__ float part[64][67];   // [row][0..63]=o1, [64]=m1, [65]=l1 (stride 67: conflict-free)
  const int tid = threadIdx.x;
  const int w = tid >> 6, lane = tid & 63;
  const int qt = blockIdx.x >> 5;          // 0..31
  const int bh = blockIdx.x & 31;          // 0..31
  const int b = bh >> 4, h = bh & 15;
  const int row = qt * 64 + lane;

  const float* qp = qkv + (size_t)(b * S_LEN + row) * QKVN + h * DH;
  const float* kb = qkv + (size_t)b * S_LEN * QKVN + DMODEL + h * DH;
  const float* vb = kb + DMODEL;

  float q[64], o[64];
#pragma unroll
  for (int d = 0; d < 64; d += 4) {
    float4 t = *(const float4*)(qp + d);
    q[d] = t.x * 0.125f; q[d + 1] = t.y * 0.125f;
    q[d + 2] = t.z * 0.125f; q[d + 3] = t.w * 0.125f;
    o[d] = 0.f; o[d + 1] = 0.f; o[d + 2] = 0.f; o[d + 3] = 0.f;
  }
  float mrun = -1e30f, lsum = 0.f;   // finite init: avoids inf-inf NaN on fully-masked lanes

  const int kn = (qt + 1) * 32;
  const int j0beg = w * kn, j0end = j0beg + kn;
  for (int j0 = j0beg; j0 < j0end; j0 += 16) {
    float sj[16];
    float tm = -INFINITY;
#pragma unroll
    for (int jj = 0; jj < 16; ++jj) {
      const int j = j0 + jj;
      const float* kr = kb + (size_t)j * QKVN;
      float s = 0.f;
#pragma unroll
      for (int d = 0; d < 64; d += 4) {
        float4 kv = *(const float4*)(kr + d);
        s += q[d] * kv.x + q[d + 1] * kv.y + q[d + 2] * kv.z + q[d + 3] * kv.w;
      }
      s = (j <= row) ? s : -INFINITY;
      sj[jj] = s;
      tm = fmaxf(tm, s);
    }
    if (tm > mrun) {                 // chunk-level rescale (rare after warmup)
      float c = __expf(mrun - tm);
      lsum *= c;
#pragma unroll
      for (int d = 0; d < 64; ++d) o[d] *= c;
      mrun = tm;
    }
#pragma unroll
    for (int jj = 0; jj < 16; ++jj) {
      const int j = j0 + jj;
      float p = __expf(sj[jj] - mrun);   // masked: exp(-inf - finite) = 0
      lsum += p;
      const float* vr = vb + (size_t)j * QKVN;
#pragma unroll
      for (int d = 0; d < 64; d += 4) {
        float4 vv = *(const float4*)(vr + d);
        o[d] += p * vv.x; o[d + 1] += p * vv.y;
        o[d + 2] += p * vv.z; o[d + 3] += p * vv.w;
      }
    }
  }

  if (w == 1) {
#pragma unroll
    for (int d = 0; d < 64; ++d) part[lane][d] = o[d];
    part[lane][64] = mrun;
    part[lane][65] = lsum;
  }
  __syncthreads();
  if (w == 0) {
    float m1 = part[lane][64], l1 = part[lane][65];
    float M = fmaxf(mrun, m1);
    float c0 = __expf(mrun - M), c1 = __expf(m1 - M);
    float l = lsum * c0 + l1 * c1;
    float inv = 1.f / l;
    unsigned short* yp = y + (size_t)(b * S_LEN + row) * DMODEL + h * DH;
#pragma unroll
    for (int d = 0; d < 64; d += 4) {
      ushort4 ov;
      ov.x = f2bf((o[d] * c0 + part[lane][d] * c1) * inv);
      ov.y = f2bf((o[d + 1] * c0 + part[lane][d + 1] * c1) * inv);
      ov.z = f2bf((o[d + 2] * c0 + part[lane][d + 2] * c1) * inv);
      ov.w = f2bf((o[d + 3] * c0 + part[lane][d + 3] * c1) * inv);
      *(ushort4*)(yp + d) = ov;
    }
  }
}

// ---------------- launch ----------------
extern "C" void kernel_launch(void* const* d_in, const int* in_sizes, int n_in,
                              void* d_out, int out_size, void* d_ws, size_t ws_size,
                              hipStream_t stream) {
  const float* x     = (const float*)d_in[0];
  const float* wqkv  = (const float*)d_in[1];
  const float* w_out = (const float*)d_in[2];
  const float* cosp  = (const float*)d_in[3];
  const float* sinp  = (const float*)d_in[4];
  const int*   tpos  = (const int*)d_in[5];
  float* out = (float*)d_out;
  char* ws = (char*)d_ws;

  // workspace layout (bytes)
  unsigned short* xb    = (unsigned short*)(ws + 0);          // 4096x1024 bf16
  unsigned short* wqkvb = (unsigned short*)(ws + 8388608);    // 3072x1024 bf16
  unsigned short* wob   = (unsigned short*)(ws + 14680064);   // 1024x1024 bf16
  float*          qkv   = (float*)(ws + 16777216);            // 4096x3072 fp32
  unsigned short* yb    = (unsigned short*)(ws + 67108864);   // 4096x1024 bf16

  cast_bf16_k<<<4096, 256, 0, stream>>>(x, xb, 1048576);
  cast_bf16_k<<<3072, 256, 0, stream>>>(wqkv, wqkvb, 786432);
  cast_bf16_k<<<1024, 256, 0, stream>>>(w_out, wob, 262144);

  gemm_bt_bf16<<<dim3(24, 32), 256, 0, stream>>>(xb, wqkvb, qkv, 4096, QKVN, 1024);

  rope_k<<<16384, 256, 0, stream>>>(qkv, cosp, sinp, tpos);

  attn_fp32_ksplit<<<1024, 128, 0, stream>>>(qkv, yb);

  gemm_bt_bf16<<<dim3(8, 32), 256, 0, stream>>>(yb, wob, out, 4096, DMODEL, 1024);
}

// Round 3
// 302.121 us; speedup vs baseline: 5.1900x; 5.1900x over previous
//
#include <hip/hip_runtime.h>
#include <hip/hip_bf16.h>

// CausalMultiHeadSelfAttention  B=2 S=2048 D_MODEL=1024 H=16 DH=64
// Pipeline: cast->bf16 | GEMM1 (bf16 out) | rope+pack (q,k roped; vT) |
//           MFMA flash attention (paired q-tiles) | GEMM2 (f32 out)

#define S_LEN 2048
#define DMODEL 1024
#define NH 16
#define QKVN 3072

typedef __attribute__((ext_vector_type(4))) short short4v;
typedef __attribute__((ext_vector_type(8))) short short8v;
typedef __attribute__((ext_vector_type(4))) float floatx4;

#define CSOFT 0.18033688f   // 0.125 * log2(e)

__device__ __forceinline__ unsigned short f2bf(float f) {
  unsigned int u = __float_as_uint(f);
  u += 0x7FFFu + ((u >> 16) & 1u);
  return (unsigned short)(u >> 16);
}
__device__ __forceinline__ float bf2f(unsigned short u) {
  return __uint_as_float(((unsigned int)u) << 16);
}
__device__ __forceinline__ void gload16(const void* g, void* l) {
  __builtin_amdgcn_global_load_lds((const __attribute__((address_space(1))) void*)g,
                                   (__attribute__((address_space(3))) void*)l,
                                   16, 0, 0);
}

// ---------------- fp32 -> bf16 cast ----------------
__global__ __launch_bounds__(256) void cast_bf16_k(const float* __restrict__ in,
                                                   unsigned short* __restrict__ out, int n4) {
  int i = blockIdx.x * 256 + threadIdx.x;
  if (i >= n4) return;
  float4 v = reinterpret_cast<const float4*>(in)[i];
  ushort4 o;
  o.x = f2bf(v.x); o.y = f2bf(v.y); o.z = f2bf(v.z); o.w = f2bf(v.w);
  reinterpret_cast<ushort4*>(out)[i] = o;
}

// ---------------- bf16 MFMA GEMM: C[M,N] = A[M,K]*B[N,K]^T ----------------
template <bool OUT_BF16>
__global__ __launch_bounds__(256) void gemm_bt(const unsigned short* __restrict__ A,
                                               const unsigned short* __restrict__ Bm,
                                               void* __restrict__ Cp, int M, int N, int K) {
  __shared__ __align__(16) unsigned short As[128 * 32];
  __shared__ __align__(16) unsigned short Bs[128 * 32];
  const int tid = threadIdx.x;
  const int lane = tid & 63;
  const int w = tid >> 6;
  const int wm = w >> 1, wn = w & 1;
  const int l15 = lane & 15, l4 = lane >> 4;
  const int bm = blockIdx.y * 128, bn = blockIdx.x * 128;
  const int srow = lane >> 2;
  const int skc = (lane & 3) * 8;

  floatx4 acc[4][4] = {};
  const short4v* As4 = (const short4v*)As;
  const short4v* Bs4 = (const short4v*)Bs;

  for (int k0 = 0; k0 < K; k0 += 32) {
#pragma unroll
    for (int j = 0; j < 2; ++j) {
      const unsigned short* ga = A + (size_t)(bm + j * 64 + w * 16 + srow) * K + k0 + skc;
      gload16(ga, &As[j * 2048 + w * 512]);
      const unsigned short* gb = Bm + (size_t)(bn + j * 64 + w * 16 + srow) * K + k0 + skc;
      gload16(gb, &Bs[j * 2048 + w * 512]);
    }
    asm volatile("s_waitcnt vmcnt(0)" ::: "memory");
    __syncthreads();

    short8v af[4], bfr[4];
#pragma unroll
    for (int f = 0; f < 4; ++f) {
      int ra = wm * 64 + f * 16 + l15;
      union { short4v h[2]; short8v v; } ua;
      ua.h[0] = As4[ra * 8 + l4];
      ua.h[1] = As4[ra * 8 + 4 + l4];
      af[f] = ua.v;
      int rb = wn * 64 + f * 16 + l15;
      union { short4v h[2]; short8v v; } ub;
      ub.h[0] = Bs4[rb * 8 + l4];
      ub.h[1] = Bs4[rb * 8 + 4 + l4];
      bfr[f] = ub.v;
    }
#pragma unroll
    for (int f = 0; f < 4; ++f)
#pragma unroll
      for (int g = 0; g < 4; ++g)
        acc[f][g] = __builtin_amdgcn_mfma_f32_16x16x32_bf16(af[f], bfr[g], acc[f][g], 0, 0, 0);
    __syncthreads();
  }

#pragma unroll
  for (int f = 0; f < 4; ++f)
#pragma unroll
    for (int g = 0; g < 4; ++g)
#pragma unroll
      for (int r = 0; r < 4; ++r) {
        int row = bm + wm * 64 + f * 16 + l4 * 4 + r;
        int col = bn + wn * 64 + g * 16 + l15;
        if (OUT_BF16)
          ((unsigned short*)Cp)[(size_t)row * N + col] = f2bf(acc[f][g][r]);
        else
          ((float*)Cp)[(size_t)row * N + col] = acc[f][g][r];
      }
}

// ---------------- rope + pack:  qkv_bf[t][3072] -> q/k packed + vT ----------------
__global__ __launch_bounds__(256) void rope_pack_k(const unsigned short* __restrict__ qkvb,
                                                   unsigned short* __restrict__ qp_,
                                                   unsigned short* __restrict__ kp_,
                                                   unsigned short* __restrict__ vtp_,
                                                   const float* __restrict__ cosp,
                                                   const float* __restrict__ sinp,
                                                   const int* __restrict__ tpos) {
  __shared__ unsigned short Vs[64][68];
  const int tid = threadIdx.x;
  const int bh = blockIdx.x >> 5;   // 0..31
  const int st = blockIdx.x & 31;   // 0..31
  const int b = bh >> 4, h = bh & 15;
  const int c = tid & 15, t0 = tid >> 4;
  const int s0 = st * 64;

#pragma unroll
  for (int it = 0; it < 4; ++it) {
    const int tl = it * 16 + t0;
    const int s = s0 + tl;
    const int tp = tpos[s];
    const size_t base = ((size_t)(b * S_LEN + s)) * QKVN + h * 64 + c * 4;
    const float co0 = cosp[tp * 32 + 2 * c], si0 = sinp[tp * 32 + 2 * c];
    const float co1 = cosp[tp * 32 + 2 * c + 1], si1 = sinp[tp * 32 + 2 * c + 1];
    // Q
    {
      ushort4 rv = *(const ushort4*)(qkvb + base);
      float a0 = bf2f(rv.x), a1 = bf2f(rv.y), a2 = bf2f(rv.z), a3 = bf2f(rv.w);
      ushort4 ov;
      ov.x = f2bf(a0 * co0 - a1 * si0); ov.y = f2bf(a0 * si0 + a1 * co0);
      ov.z = f2bf(a2 * co1 - a3 * si1); ov.w = f2bf(a2 * si1 + a3 * co1);
      *(ushort4*)(qp_ + ((size_t)bh * S_LEN + s) * 64 + c * 4) = ov;
    }
    // K
    {
      ushort4 rv = *(const ushort4*)(qkvb + base + DMODEL);
      float a0 = bf2f(rv.x), a1 = bf2f(rv.y), a2 = bf2f(rv.z), a3 = bf2f(rv.w);
      ushort4 ov;
      ov.x = f2bf(a0 * co0 - a1 * si0); ov.y = f2bf(a0 * si0 + a1 * co0);
      ov.z = f2bf(a2 * co1 - a3 * si1); ov.w = f2bf(a2 * si1 + a3 * co1);
      *(ushort4*)(kp_ + ((size_t)bh * S_LEN + s) * 64 + c * 4) = ov;
    }
    // V -> LDS
    {
      ushort4 rv = *(const ushort4*)(qkvb + base + 2 * DMODEL);
      *(ushort4*)(&Vs[tl][c * 4]) = rv;
    }
  }
  __syncthreads();
  // transposed V write: row d, cols s0+c*4..+3
#pragma unroll
  for (int it = 0; it < 4; ++it) {
    const int d = it * 16 + t0;
    ushort4 ov;
    ov.x = Vs[c * 4 + 0][d]; ov.y = Vs[c * 4 + 1][d];
    ov.z = Vs[c * 4 + 2][d]; ov.w = Vs[c * 4 + 3][d];
    *(ushort4*)(vtp_ + ((size_t)bh * 64 + d) * S_LEN + s0 + c * 4) = ov;
  }
}

// ---------------- MFMA flash attention ----------------
// LDS frag read with XOR swizzle: logical [row][64] bf16, chunk(16B) c stored at c^(row&7)
__device__ __forceinline__ short8v readfrag(const unsigned short* L, int row, int c2, int l4) {
  const int sw = row & 7;
  const int cl = c2 * 4 + (l4 >> 1);
  const int base = row * 64 + (l4 & 1) * 4;
  union { short4v h[2]; short8v v; } u;
  u.h[0] = *(const short4v*)(L + base + ((cl ^ sw) << 3));
  u.h[1] = *(const short4v*)(L + base + (((cl + 2) ^ sw) << 3));
  return u.v;
}

__global__ __launch_bounds__(256) void attn_mfma(const unsigned short* __restrict__ qp_,
                                                 const unsigned short* __restrict__ kp_,
                                                 const unsigned short* __restrict__ vtp_,
                                                 unsigned short* __restrict__ yb) {
  __shared__ __align__(16) unsigned short Kl[4096];
  __shared__ __align__(16) unsigned short Vl[4096];
  const int tid = threadIdx.x;
  const int lane = tid & 63, w = tid >> 6;     // w = wave = q-strip
  const int l15 = lane & 15, l4 = lane >> 4;
  const int bh = blockIdx.x >> 4;              // 0..31
  const int pair = blockIdx.x & 15;            // 0..15
  const int b = bh >> 4, h = bh & 15;

  const unsigned short* kg0 = kp_ + (size_t)bh * S_LEN * 64;
  const unsigned short* vg0 = vtp_ + (size_t)bh * 64 * S_LEN;

  for (int pass = 0; pass < 2; ++pass) {
    const int qt = pass ? pair : 31 - pair;    // big tile first
    // Q fragments (registers)
    const unsigned short* qp = qp_ + ((size_t)bh * S_LEN + qt * 64 + w * 16 + l15) * 64;
    short8v qf[2];
#pragma unroll
    for (int c2 = 0; c2 < 2; ++c2) {
      union { short4v h[2]; short8v v; } u;
      u.h[0] = *(const short4v*)(qp + c2 * 32 + 4 * l4);
      u.h[1] = *(const short4v*)(qp + c2 * 32 + 16 + 4 * l4);
      qf[c2] = u.v;
    }
    floatx4 o[4] = {};
    float mrun = -1e30f, lsum = 0.f;

    for (int kt = 0; kt <= qt; ++kt) {
      // stage K tile [64][64] and vT tile [64][64], swizzled global source
#pragma unroll
      for (int i = 0; i < 2; ++i) {
        int jj = i * 256 + tid;
        int row = jj >> 3;
        int cc = (jj & 7) ^ (row & 7);
        gload16(kg0 + (size_t)kt * 4096 + row * 64 + cc * 8, &Kl[(i * 256 + w * 64) * 8]);
        gload16(vg0 + (size_t)row * S_LEN + kt * 64 + cc * 8, &Vl[(i * 256 + w * 64) * 8]);
      }
      asm volatile("s_waitcnt vmcnt(0)" ::: "memory");
      __syncthreads();

      const bool diag = (kt == qt);
      float s_[4][4];
#pragma unroll
      for (int g = 0; g < 4; ++g) {
        if (diag && g > w) {
          s_[g][0] = s_[g][1] = s_[g][2] = s_[g][3] = -INFINITY;
          continue;
        }
        short8v k0 = readfrag(Kl, g * 16 + l15, 0, l4);
        short8v k1 = readfrag(Kl, g * 16 + l15, 1, l4);
        floatx4 t = {0.f, 0.f, 0.f, 0.f};
        t = __builtin_amdgcn_mfma_f32_16x16x32_bf16(k0, qf[0], t, 0, 0, 0);
        t = __builtin_amdgcn_mfma_f32_16x16x32_bf16(k1, qf[1], t, 0, 0, 0);
#pragma unroll
        for (int r = 0; r < 4; ++r) {
          float v = t[r];
          if (diag && g == w && (l4 * 4 + r > l15)) v = -INFINITY;
          s_[g][r] = v;
        }
      }
      // online softmax (per-lane row = q = l15; 4 copies across l4)
      float tm = -INFINITY;
#pragma unroll
      for (int g = 0; g < 4; ++g)
#pragma unroll
        for (int r = 0; r < 4; ++r) tm = fmaxf(tm, s_[g][r]);
      tm = fmaxf(tm, __shfl_xor(tm, 16));
      tm = fmaxf(tm, __shfl_xor(tm, 32));
      float nm = fmaxf(mrun, tm);
      float rs = exp2f((mrun - nm) * CSOFT);
      mrun = nm;
      lsum *= rs;
      float rsr[4];
#pragma unroll
      for (int r = 0; r < 4; ++r) rsr[r] = __shfl(rs, l4 * 4 + r);
#pragma unroll
      for (int dt = 0; dt < 4; ++dt)
#pragma unroll
        for (int r = 0; r < 4; ++r) o[dt][r] *= rsr[r];

      union { unsigned short u[16]; short8v v[2]; } pk;
      float psum = 0.f;
#pragma unroll
      for (int g = 0; g < 4; ++g)
#pragma unroll
        for (int r = 0; r < 4; ++r) {
          float p = exp2f((s_[g][r] - mrun) * CSOFT);
          psum += p;
          pk.u[g * 4 + r] = f2bf(p);
        }
      lsum += psum;
      // PV
#pragma unroll
      for (int dt = 0; dt < 4; ++dt) {
        short8v v0 = readfrag(Vl, dt * 16 + l15, 0, l4);
        short8v v1 = readfrag(Vl, dt * 16 + l15, 1, l4);
        o[dt] = __builtin_amdgcn_mfma_f32_16x16x32_bf16(pk.v[0], v0, o[dt], 0, 0, 0);
        o[dt] = __builtin_amdgcn_mfma_f32_16x16x32_bf16(pk.v[1], v1, o[dt], 0, 0, 0);
      }
      __syncthreads();
    }
    // epilogue: full row-sum, normalize, store (o rows: q = l4*4+r)
    lsum += __shfl_xor(lsum, 16);
    lsum += __shfl_xor(lsum, 32);
    float linv = 1.f / lsum;
    float lr[4];
#pragma unroll
    for (int r = 0; r < 4; ++r) lr[r] = __shfl(linv, l4 * 4 + r);
#pragma unroll
    for (int dt = 0; dt < 4; ++dt)
#pragma unroll
      for (int r = 0; r < 4; ++r) {
        size_t row = (size_t)(b * S_LEN + qt * 64 + w * 16 + l4 * 4 + r);
        yb[row * DMODEL + h * 64 + dt * 16 + l15] = f2bf(o[dt][r] * lr[r]);
      }
  }
}

// ---------------- launch ----------------
extern "C" void kernel_launch(void* const* d_in, const int* in_sizes, int n_in,
                              void* d_out, int out_size, void* d_ws, size_t ws_size,
                              hipStream_t stream) {
  const float* x     = (const float*)d_in[0];
  const float* wqkv  = (const float*)d_in[1];
  const float* w_out = (const float*)d_in[2];
  const float* cosp  = (const float*)d_in[3];
  const float* sinp  = (const float*)d_in[4];
  const int*   tpos  = (const int*)d_in[5];
  float* out = (float*)d_out;
  char* ws = (char*)d_ws;

  const size_t MB = 1024 * 1024;
  unsigned short* xb    = (unsigned short*)(ws + 0);        // 8 MB   (dead after gemm1)
  unsigned short* wqkvb = (unsigned short*)(ws + 8 * MB);   // 6 MB   (dead after gemm1)
  unsigned short* wob   = (unsigned short*)(ws + 14 * MB);  // 2 MB   (live to end)
  unsigned short* qkvb  = (unsigned short*)(ws + 16 * MB);  // 24 MB  (dead after pack)
  unsigned short* qpk   = (unsigned short*)(ws + 40 * MB);  // 8 MB
  unsigned short* kpk   = (unsigned short*)(ws + 48 * MB);  // 8 MB
  unsigned short* vtpk  = (unsigned short*)(ws + 56 * MB);  // 8 MB
  unsigned short* yb    = (unsigned short*)(ws + 0);        // 8 MB   (reuse xb region)

  cast_bf16_k<<<4096, 256, 0, stream>>>(x, xb, 1048576);
  cast_bf16_k<<<3072, 256, 0, stream>>>(wqkv, wqkvb, 786432);
  cast_bf16_k<<<1024, 256, 0, stream>>>(w_out, wob, 262144);

  gemm_bt<true><<<dim3(24, 32), 256, 0, stream>>>(xb, wqkvb, qkvb, 4096, QKVN, 1024);

  rope_pack_k<<<1024, 256, 0, stream>>>(qkvb, qpk, kpk, vtpk, cosp, sinp, tpos);

  attn_mfma<<<512, 256, 0, stream>>>(qpk, kpk, vtpk, yb);

  gemm_bt<false><<<dim3(8, 32), 256, 0, stream>>>(yb, wob, out, 4096, DMODEL, 1024);
}

// Round 4
// 229.219 us; speedup vs baseline: 6.8407x; 1.3180x over previous
//
#include <hip/hip_runtime.h>
#include <hip/hip_bf16.h>

// CausalMultiHeadSelfAttention  B=2 S=2048 D_MODEL=1024 H=16 DH=64
// Pipeline: cast->bf16 (k-permuted) | GEMM1 | rope+pack | MFMA flash attn | GEMM2
//
// k-permutation: all GEMM operands store k in 32-blocks as chunk c (8 bf16) =
// logical {4c..4c+3, 16+4c..16+4c+3}. This makes the 16x16x32 MFMA A/B fragment
// for lane-group l4 a single contiguous 16B -> one conflict-free ds_read_b128,
// while global_load_lds staging stays linear. Both operands permuted -> dot
// product unchanged.

#define S_LEN 2048
#define DMODEL 1024
#define NH 16
#define QKVN 3072

typedef __attribute__((ext_vector_type(4))) short short4v;
typedef __attribute__((ext_vector_type(8))) short short8v;
typedef __attribute__((ext_vector_type(4))) float floatx4;

#define CSOFT 0.18033688f   // 0.125 * log2(e)

__device__ __forceinline__ unsigned short f2bf(float f) {
  unsigned int u = __float_as_uint(f);
  u += 0x7FFFu + ((u >> 16) & 1u);
  return (unsigned short)(u >> 16);
}
__device__ __forceinline__ float bf2f(unsigned short u) {
  return __uint_as_float(((unsigned int)u) << 16);
}
__device__ __forceinline__ void gload16(const void* g, void* l) {
  __builtin_amdgcn_global_load_lds((const __attribute__((address_space(1))) void*)g,
                                   (__attribute__((address_space(3))) void*)l,
                                   16, 0, 0);
}

// ---------------- fp32 -> bf16 cast with k-block permutation ----------------
// out chunk i (8 bf16): block = i>>2, c = i&3;
// elems = logical float4 at (block*8 + c) and (block*8 + 4 + c)
__global__ __launch_bounds__(256) void cast_bf16_perm_k(const float* __restrict__ in,
                                                        unsigned short* __restrict__ out,
                                                        int nchunk) {
  int i = blockIdx.x * 256 + threadIdx.x;
  if (i >= nchunk) return;
  int c = i & 3;
  const float4* f4 = reinterpret_cast<const float4*>(in);
  float4 lo = f4[(i >> 2) * 8 + c];
  float4 hi = f4[(i >> 2) * 8 + 4 + c];
  short8v o;
  o[0] = (short)f2bf(lo.x); o[1] = (short)f2bf(lo.y);
  o[2] = (short)f2bf(lo.z); o[3] = (short)f2bf(lo.w);
  o[4] = (short)f2bf(hi.x); o[5] = (short)f2bf(hi.y);
  o[6] = (short)f2bf(hi.z); o[7] = (short)f2bf(hi.w);
  reinterpret_cast<short8v*>(out)[i] = o;
}

// ---------------- bf16 MFMA GEMM: C[M,N] = A[M,K]*B[N,K]^T (A,B k-permuted) ----------------
template <bool OUT_BF16>
__global__ __launch_bounds__(256) void gemm_bt(const unsigned short* __restrict__ A,
                                               const unsigned short* __restrict__ Bm,
                                               void* __restrict__ Cp, int M, int N, int K) {
  __shared__ __align__(16) unsigned short As[128 * 32];
  __shared__ __align__(16) unsigned short Bs[128 * 32];
  const int tid = threadIdx.x;
  const int lane = tid & 63;
  const int w = tid >> 6;
  const int wm = w >> 1, wn = w & 1;
  const int l15 = lane & 15, l4 = lane >> 4;
  const int bm = blockIdx.y * 128, bn = blockIdx.x * 128;
  const int srow = lane >> 2;
  const int skc = (lane & 3) * 8;

  floatx4 acc[4][4] = {};

  for (int k0 = 0; k0 < K; k0 += 32) {
#pragma unroll
    for (int j = 0; j < 2; ++j) {
      const unsigned short* ga = A + (size_t)(bm + j * 64 + w * 16 + srow) * K + k0 + skc;
      gload16(ga, &As[j * 2048 + w * 512]);
      const unsigned short* gb = Bm + (size_t)(bn + j * 64 + w * 16 + srow) * K + k0 + skc;
      gload16(gb, &Bs[j * 2048 + w * 512]);
    }
    asm volatile("s_waitcnt vmcnt(0)" ::: "memory");
    __syncthreads();

    // fragment = stored chunk l4 of row: single ds_read_b128, conflict-free
    short8v af[4], bfr[4];
#pragma unroll
    for (int f = 0; f < 4; ++f) {
      af[f]  = *(const short8v*)(As + (wm * 64 + f * 16 + l15) * 32 + l4 * 8);
      bfr[f] = *(const short8v*)(Bs + (wn * 64 + f * 16 + l15) * 32 + l4 * 8);
    }
#pragma unroll
    for (int f = 0; f < 4; ++f)
#pragma unroll
      for (int g = 0; g < 4; ++g)
        acc[f][g] = __builtin_amdgcn_mfma_f32_16x16x32_bf16(af[f], bfr[g], acc[f][g], 0, 0, 0);
    __syncthreads();
  }

#pragma unroll
  for (int f = 0; f < 4; ++f)
#pragma unroll
    for (int g = 0; g < 4; ++g)
#pragma unroll
      for (int r = 0; r < 4; ++r) {
        int row = bm + wm * 64 + f * 16 + l4 * 4 + r;
        int col = bn + wn * 64 + g * 16 + l15;
        if (OUT_BF16)
          ((unsigned short*)Cp)[(size_t)row * N + col] = f2bf(acc[f][g][r]);
        else
          ((float*)Cp)[(size_t)row * N + col] = acc[f][g][r];
      }
}

// ---------------- rope + pack:  qkv_bf[t][3072] -> q/k packed + vT ----------------
__global__ __launch_bounds__(256) void rope_pack_k(const unsigned short* __restrict__ qkvb,
                                                   unsigned short* __restrict__ qp_,
                                                   unsigned short* __restrict__ kp_,
                                                   unsigned short* __restrict__ vtp_,
                                                   const float* __restrict__ cosp,
                                                   const float* __restrict__ sinp,
                                                   const int* __restrict__ tpos) {
  __shared__ unsigned short Vs[64][68];
  const int tid = threadIdx.x;
  const int bh = blockIdx.x >> 5;   // 0..31
  const int st = blockIdx.x & 31;   // 0..31
  const int b = bh >> 4, h = bh & 15;
  const int c = tid & 15, t0 = tid >> 4;
  const int s0 = st * 64;

#pragma unroll
  for (int it = 0; it < 4; ++it) {
    const int tl = it * 16 + t0;
    const int s = s0 + tl;
    const int tp = tpos[s];
    const size_t base = ((size_t)(b * S_LEN + s)) * QKVN + h * 64 + c * 4;
    const float co0 = cosp[tp * 32 + 2 * c], si0 = sinp[tp * 32 + 2 * c];
    const float co1 = cosp[tp * 32 + 2 * c + 1], si1 = sinp[tp * 32 + 2 * c + 1];
    // Q
    {
      ushort4 rv = *(const ushort4*)(qkvb + base);
      float a0 = bf2f(rv.x), a1 = bf2f(rv.y), a2 = bf2f(rv.z), a3 = bf2f(rv.w);
      ushort4 ov;
      ov.x = f2bf(a0 * co0 - a1 * si0); ov.y = f2bf(a0 * si0 + a1 * co0);
      ov.z = f2bf(a2 * co1 - a3 * si1); ov.w = f2bf(a2 * si1 + a3 * co1);
      *(ushort4*)(qp_ + ((size_t)bh * S_LEN + s) * 64 + c * 4) = ov;
    }
    // K
    {
      ushort4 rv = *(const ushort4*)(qkvb + base + DMODEL);
      float a0 = bf2f(rv.x), a1 = bf2f(rv.y), a2 = bf2f(rv.z), a3 = bf2f(rv.w);
      ushort4 ov;
      ov.x = f2bf(a0 * co0 - a1 * si0); ov.y = f2bf(a0 * si0 + a1 * co0);
      ov.z = f2bf(a2 * co1 - a3 * si1); ov.w = f2bf(a2 * si1 + a3 * co1);
      *(ushort4*)(kp_ + ((size_t)bh * S_LEN + s) * 64 + c * 4) = ov;
    }
    // V -> LDS
    {
      ushort4 rv = *(const ushort4*)(qkvb + base + 2 * DMODEL);
      *(ushort4*)(&Vs[tl][c * 4]) = rv;
    }
  }
  __syncthreads();
#pragma unroll
  for (int it = 0; it < 4; ++it) {
    const int d = it * 16 + t0;
    ushort4 ov;
    ov.x = Vs[c * 4 + 0][d]; ov.y = Vs[c * 4 + 1][d];
    ov.z = Vs[c * 4 + 2][d]; ov.w = Vs[c * 4 + 3][d];
    *(ushort4*)(vtp_ + ((size_t)bh * 64 + d) * S_LEN + s0 + c * 4) = ov;
  }
}

// ---------------- MFMA flash attention ----------------
// LDS frag read with XOR swizzle: logical [row][64] bf16, chunk(16B) c stored at c^(row&7)
__device__ __forceinline__ short8v readfrag(const unsigned short* L, int row, int c2, int l4) {
  const int sw = row & 7;
  const int cl = c2 * 4 + (l4 >> 1);
  const int base = row * 64 + (l4 & 1) * 4;
  union { short4v h[2]; short8v v; } u;
  u.h[0] = *(const short4v*)(L + base + ((cl ^ sw) << 3));
  u.h[1] = *(const short4v*)(L + base + (((cl + 2) ^ sw) << 3));
  return u.v;
}

__global__ __launch_bounds__(256) void attn_mfma(const unsigned short* __restrict__ qp_,
                                                 const unsigned short* __restrict__ kp_,
                                                 const unsigned short* __restrict__ vtp_,
                                                 unsigned short* __restrict__ yb) {
  __shared__ __align__(16) unsigned short Kl[4096];
  __shared__ __align__(16) unsigned short Vl[4096];
  const int tid = threadIdx.x;
  const int lane = tid & 63, w = tid >> 6;     // w = wave = q-strip
  const int l15 = lane & 15, l4 = lane >> 4;
  const int bh = blockIdx.x >> 4;              // 0..31
  const int pair = blockIdx.x & 15;            // 0..15
  const int b = bh >> 4, h = bh & 15;

  const unsigned short* kg0 = kp_ + (size_t)bh * S_LEN * 64;
  const unsigned short* vg0 = vtp_ + (size_t)bh * 64 * S_LEN;

  for (int pass = 0; pass < 2; ++pass) {
    const int qt = pass ? pair : 31 - pair;    // big tile first
    const unsigned short* qp = qp_ + ((size_t)bh * S_LEN + qt * 64 + w * 16 + l15) * 64;
    short8v qf[2];
#pragma unroll
    for (int c2 = 0; c2 < 2; ++c2) {
      union { short4v h[2]; short8v v; } u;
      u.h[0] = *(const short4v*)(qp + c2 * 32 + 4 * l4);
      u.h[1] = *(const short4v*)(qp + c2 * 32 + 16 + 4 * l4);
      qf[c2] = u.v;
    }
    floatx4 o[4] = {};
    float mrun = -1e30f, lsum = 0.f;

    for (int kt = 0; kt <= qt; ++kt) {
#pragma unroll
      for (int i = 0; i < 2; ++i) {
        int jj = i * 256 + tid;
        int row = jj >> 3;
        int cc = (jj & 7) ^ (row & 7);
        gload16(kg0 + (size_t)kt * 4096 + row * 64 + cc * 8, &Kl[(i * 256 + w * 64) * 8]);
        gload16(vg0 + (size_t)row * S_LEN + kt * 64 + cc * 8, &Vl[(i * 256 + w * 64) * 8]);
      }
      asm volatile("s_waitcnt vmcnt(0)" ::: "memory");
      __syncthreads();

      const bool diag = (kt == qt);
      float s_[4][4];
#pragma unroll
      for (int g = 0; g < 4; ++g) {
        if (diag && g > w) {
          s_[g][0] = s_[g][1] = s_[g][2] = s_[g][3] = -INFINITY;
          continue;
        }
        short8v k0 = readfrag(Kl, g * 16 + l15, 0, l4);
        short8v k1 = readfrag(Kl, g * 16 + l15, 1, l4);
        floatx4 t = {0.f, 0.f, 0.f, 0.f};
        t = __builtin_amdgcn_mfma_f32_16x16x32_bf16(k0, qf[0], t, 0, 0, 0);
        t = __builtin_amdgcn_mfma_f32_16x16x32_bf16(k1, qf[1], t, 0, 0, 0);
#pragma unroll
        for (int r = 0; r < 4; ++r) {
          float v = t[r];
          if (diag && g == w && (l4 * 4 + r > l15)) v = -INFINITY;
          s_[g][r] = v;
        }
      }
      float tm = -INFINITY;
#pragma unroll
      for (int g = 0; g < 4; ++g)
#pragma unroll
        for (int r = 0; r < 4; ++r) tm = fmaxf(tm, s_[g][r]);
      tm = fmaxf(tm, __shfl_xor(tm, 16));
      tm = fmaxf(tm, __shfl_xor(tm, 32));
      float nm = fmaxf(mrun, tm);
      float rs = exp2f((mrun - nm) * CSOFT);
      mrun = nm;
      lsum *= rs;
      float rsr[4];
#pragma unroll
      for (int r = 0; r < 4; ++r) rsr[r] = __shfl(rs, l4 * 4 + r);
#pragma unroll
      for (int dt = 0; dt < 4; ++dt)
#pragma unroll
        for (int r = 0; r < 4; ++r) o[dt][r] *= rsr[r];

      union { unsigned short u[16]; short8v v[2]; } pk;
      float psum = 0.f;
#pragma unroll
      for (int g = 0; g < 4; ++g)
#pragma unroll
        for (int r = 0; r < 4; ++r) {
          float p = exp2f((s_[g][r] - mrun) * CSOFT);
          psum += p;
          pk.u[g * 4 + r] = f2bf(p);
        }
      lsum += psum;
#pragma unroll
      for (int dt = 0; dt < 4; ++dt) {
        short8v v0 = readfrag(Vl, dt * 16 + l15, 0, l4);
        short8v v1 = readfrag(Vl, dt * 16 + l15, 1, l4);
        o[dt] = __builtin_amdgcn_mfma_f32_16x16x32_bf16(pk.v[0], v0, o[dt], 0, 0, 0);
        o[dt] = __builtin_amdgcn_mfma_f32_16x16x32_bf16(pk.v[1], v1, o[dt], 0, 0, 0);
      }
      __syncthreads();
    }
    lsum += __shfl_xor(lsum, 16);
    lsum += __shfl_xor(lsum, 32);
    float linv = 1.f / lsum;
    float lr[4];
#pragma unroll
    for (int r = 0; r < 4; ++r) lr[r] = __shfl(linv, l4 * 4 + r);
    // yb store, k-permuted columns for GEMM2's A operand:
    // logical col = h*64 + dt*16 + l15 -> block (h*2+(dt>>1)),
    // stored offset = (l15>>2)*8 + (l15&3) + 4*(dt&1)
#pragma unroll
    for (int dt = 0; dt < 4; ++dt)
#pragma unroll
      for (int r = 0; r < 4; ++r) {
        size_t row = (size_t)(b * S_LEN + qt * 64 + w * 16 + l4 * 4 + r);
        int col = (h * 2 + (dt >> 1)) * 32 + (l15 >> 2) * 8 + (l15 & 3) + 4 * (dt & 1);
        yb[row * DMODEL + col] = f2bf(o[dt][r] * lr[r]);
      }
  }
}

// ---------------- launch ----------------
extern "C" void kernel_launch(void* const* d_in, const int* in_sizes, int n_in,
                              void* d_out, int out_size, void* d_ws, size_t ws_size,
                              hipStream_t stream) {
  const float* x     = (const float*)d_in[0];
  const float* wqkv  = (const float*)d_in[1];
  const float* w_out = (const float*)d_in[2];
  const float* cosp  = (const float*)d_in[3];
  const float* sinp  = (const float*)d_in[4];
  const int*   tpos  = (const int*)d_in[5];
  float* out = (float*)d_out;
  char* ws = (char*)d_ws;

  const size_t MB = 1024 * 1024;
  unsigned short* xb    = (unsigned short*)(ws + 0);        // 8 MB
  unsigned short* wqkvb = (unsigned short*)(ws + 8 * MB);   // 6 MB
  unsigned short* wob   = (unsigned short*)(ws + 14 * MB);  // 2 MB
  unsigned short* qkvb  = (unsigned short*)(ws + 16 * MB);  // 24 MB
  unsigned short* qpk   = (unsigned short*)(ws + 40 * MB);  // 8 MB
  unsigned short* kpk   = (unsigned short*)(ws + 48 * MB);  // 8 MB
  unsigned short* vtpk  = (unsigned short*)(ws + 56 * MB);  // 8 MB
  unsigned short* yb    = (unsigned short*)(ws + 0);        // 8 MB (reuse xb)

  cast_bf16_perm_k<<<2048, 256, 0, stream>>>(x, xb, 524288);
  cast_bf16_perm_k<<<1536, 256, 0, stream>>>(wqkv, wqkvb, 393216);
  cast_bf16_perm_k<<<512, 256, 0, stream>>>(w_out, wob, 131072);

  gemm_bt<true><<<dim3(24, 32), 256, 0, stream>>>(xb, wqkvb, qkvb, 4096, QKVN, 1024);

  rope_pack_k<<<1024, 256, 0, stream>>>(qkvb, qpk, kpk, vtpk, cosp, sinp, tpos);

  attn_mfma<<<512, 256, 0, stream>>>(qpk, kpk, vtpk, yb);

  gemm_bt<false><<<dim3(8, 32), 256, 0, stream>>>(yb, wob, out, 4096, DMODEL, 1024);
}

// Round 5
// 221.798 us; speedup vs baseline: 7.0696x; 1.0335x over previous
//
#include <hip/hip_runtime.h>
#include <hip/hip_bf16.h>

// CausalMultiHeadSelfAttention  B=2 S=2048 D_MODEL=1024 H=16 DH=64
// Pipeline: cast->bf16 (k-permuted) | GEMM1 | rope+pack (Q pre-scaled by
// 0.125*log2e) | MFMA flash attn (XCD-grouped, double-buffered, defer-max) |
// GEMM2
//
// k-permutation: all GEMM operands store k in 32-blocks as chunk c (8 bf16) =
// logical {4c..4c+3, 16+4c..16+4c+3} -> MFMA fragment = one ds_read_b128.

#define S_LEN 2048
#define DMODEL 1024
#define NH 16
#define QKVN 3072

typedef __attribute__((ext_vector_type(4))) short short4v;
typedef __attribute__((ext_vector_type(8))) short short8v;
typedef __attribute__((ext_vector_type(4))) float floatx4;

#define CSOFT 0.18033688f   // 0.125 * log2(e): folded into Q at pack time

__device__ __forceinline__ unsigned short f2bf(float f) {
  unsigned int u = __float_as_uint(f);
  u += 0x7FFFu + ((u >> 16) & 1u);
  return (unsigned short)(u >> 16);
}
__device__ __forceinline__ float bf2f(unsigned short u) {
  return __uint_as_float(((unsigned int)u) << 16);
}
__device__ __forceinline__ void gload16(const void* g, void* l) {
  __builtin_amdgcn_global_load_lds((const __attribute__((address_space(1))) void*)g,
                                   (__attribute__((address_space(3))) void*)l,
                                   16, 0, 0);
}

// ---------------- fp32 -> bf16 cast with k-block permutation ----------------
__global__ __launch_bounds__(256) void cast_bf16_perm_k(const float* __restrict__ in,
                                                        unsigned short* __restrict__ out,
                                                        int nchunk) {
  int i = blockIdx.x * 256 + threadIdx.x;
  if (i >= nchunk) return;
  int c = i & 3;
  const float4* f4 = reinterpret_cast<const float4*>(in);
  float4 lo = f4[(i >> 2) * 8 + c];
  float4 hi = f4[(i >> 2) * 8 + 4 + c];
  short8v o;
  o[0] = (short)f2bf(lo.x); o[1] = (short)f2bf(lo.y);
  o[2] = (short)f2bf(lo.z); o[3] = (short)f2bf(lo.w);
  o[4] = (short)f2bf(hi.x); o[5] = (short)f2bf(hi.y);
  o[6] = (short)f2bf(hi.z); o[7] = (short)f2bf(hi.w);
  reinterpret_cast<short8v*>(out)[i] = o;
}

// ---------------- bf16 MFMA GEMM: C[M,N] = A[M,K]*B[N,K]^T (A,B k-permuted) ----------------
template <bool OUT_BF16>
__global__ __launch_bounds__(256) void gemm_bt(const unsigned short* __restrict__ A,
                                               const unsigned short* __restrict__ Bm,
                                               void* __restrict__ Cp, int M, int N, int K) {
  __shared__ __align__(16) unsigned short As[128 * 32];
  __shared__ __align__(16) unsigned short Bs[128 * 32];
  const int tid = threadIdx.x;
  const int lane = tid & 63;
  const int w = tid >> 6;
  const int wm = w >> 1, wn = w & 1;
  const int l15 = lane & 15, l4 = lane >> 4;
  const int bm = blockIdx.y * 128, bn = blockIdx.x * 128;
  const int srow = lane >> 2;
  const int skc = (lane & 3) * 8;

  floatx4 acc[4][4] = {};

  for (int k0 = 0; k0 < K; k0 += 32) {
#pragma unroll
    for (int j = 0; j < 2; ++j) {
      const unsigned short* ga = A + (size_t)(bm + j * 64 + w * 16 + srow) * K + k0 + skc;
      gload16(ga, &As[j * 2048 + w * 512]);
      const unsigned short* gb = Bm + (size_t)(bn + j * 64 + w * 16 + srow) * K + k0 + skc;
      gload16(gb, &Bs[j * 2048 + w * 512]);
    }
    asm volatile("s_waitcnt vmcnt(0)" ::: "memory");
    __syncthreads();

    short8v af[4], bfr[4];
#pragma unroll
    for (int f = 0; f < 4; ++f) {
      af[f]  = *(const short8v*)(As + (wm * 64 + f * 16 + l15) * 32 + l4 * 8);
      bfr[f] = *(const short8v*)(Bs + (wn * 64 + f * 16 + l15) * 32 + l4 * 8);
    }
#pragma unroll
    for (int f = 0; f < 4; ++f)
#pragma unroll
      for (int g = 0; g < 4; ++g)
        acc[f][g] = __builtin_amdgcn_mfma_f32_16x16x32_bf16(af[f], bfr[g], acc[f][g], 0, 0, 0);
    __syncthreads();
  }

#pragma unroll
  for (int f = 0; f < 4; ++f)
#pragma unroll
    for (int g = 0; g < 4; ++g)
#pragma unroll
      for (int r = 0; r < 4; ++r) {
        int row = bm + wm * 64 + f * 16 + l4 * 4 + r;
        int col = bn + wn * 64 + g * 16 + l15;
        if (OUT_BF16)
          ((unsigned short*)Cp)[(size_t)row * N + col] = f2bf(acc[f][g][r]);
        else
          ((float*)Cp)[(size_t)row * N + col] = acc[f][g][r];
      }
}

// ---------------- rope + pack ----------------
// Q gets cos/sin pre-scaled by CSOFT so attention scores are in log2 units.
__global__ __launch_bounds__(256) void rope_pack_k(const unsigned short* __restrict__ qkvb,
                                                   unsigned short* __restrict__ qp_,
                                                   unsigned short* __restrict__ kp_,
                                                   unsigned short* __restrict__ vtp_,
                                                   const float* __restrict__ cosp,
                                                   const float* __restrict__ sinp,
                                                   const int* __restrict__ tpos) {
  __shared__ unsigned short Vs[64][68];
  const int tid = threadIdx.x;
  const int bh = blockIdx.x >> 5;
  const int st = blockIdx.x & 31;
  const int b = bh >> 4, h = bh & 15;
  const int c = tid & 15, t0 = tid >> 4;
  const int s0 = st * 64;

#pragma unroll
  for (int it = 0; it < 4; ++it) {
    const int tl = it * 16 + t0;
    const int s = s0 + tl;
    const int tp = tpos[s];
    const size_t base = ((size_t)(b * S_LEN + s)) * QKVN + h * 64 + c * 4;
    const float co0 = cosp[tp * 32 + 2 * c], si0 = sinp[tp * 32 + 2 * c];
    const float co1 = cosp[tp * 32 + 2 * c + 1], si1 = sinp[tp * 32 + 2 * c + 1];
    // Q (scaled)
    {
      const float c0 = co0 * CSOFT, s0q = si0 * CSOFT;
      const float c1 = co1 * CSOFT, s1q = si1 * CSOFT;
      ushort4 rv = *(const ushort4*)(qkvb + base);
      float a0 = bf2f(rv.x), a1 = bf2f(rv.y), a2 = bf2f(rv.z), a3 = bf2f(rv.w);
      ushort4 ov;
      ov.x = f2bf(a0 * c0 - a1 * s0q); ov.y = f2bf(a0 * s0q + a1 * c0);
      ov.z = f2bf(a2 * c1 - a3 * s1q); ov.w = f2bf(a2 * s1q + a3 * c1);
      *(ushort4*)(qp_ + ((size_t)bh * S_LEN + s) * 64 + c * 4) = ov;
    }
    // K
    {
      ushort4 rv = *(const ushort4*)(qkvb + base + DMODEL);
      float a0 = bf2f(rv.x), a1 = bf2f(rv.y), a2 = bf2f(rv.z), a3 = bf2f(rv.w);
      ushort4 ov;
      ov.x = f2bf(a0 * co0 - a1 * si0); ov.y = f2bf(a0 * si0 + a1 * co0);
      ov.z = f2bf(a2 * co1 - a3 * si1); ov.w = f2bf(a2 * si1 + a3 * co1);
      *(ushort4*)(kp_ + ((size_t)bh * S_LEN + s) * 64 + c * 4) = ov;
    }
    // V -> LDS
    {
      ushort4 rv = *(const ushort4*)(qkvb + base + 2 * DMODEL);
      *(ushort4*)(&Vs[tl][c * 4]) = rv;
    }
  }
  __syncthreads();
#pragma unroll
  for (int it = 0; it < 4; ++it) {
    const int d = it * 16 + t0;
    ushort4 ov;
    ov.x = Vs[c * 4 + 0][d]; ov.y = Vs[c * 4 + 1][d];
    ov.z = Vs[c * 4 + 2][d]; ov.w = Vs[c * 4 + 3][d];
    *(ushort4*)(vtp_ + ((size_t)bh * 64 + d) * S_LEN + s0 + c * 4) = ov;
  }
}

// ---------------- MFMA flash attention ----------------
__device__ __forceinline__ short8v readfrag(const unsigned short* L, int row, int c2, int l4) {
  const int sw = row & 7;
  const int cl = c2 * 4 + (l4 >> 1);
  const int base = row * 64 + (l4 & 1) * 4;
  union { short4v h[2]; short8v v; } u;
  u.h[0] = *(const short4v*)(L + base + ((cl ^ sw) << 3));
  u.h[1] = *(const short4v*)(L + base + (((cl + 2) ^ sw) << 3));
  return u.v;
}

__device__ __forceinline__ void stage_tiles(const unsigned short* kg0, const unsigned short* vg0,
                                            int kt, unsigned short* Kb, unsigned short* Vb,
                                            int tid, int w) {
#pragma unroll
  for (int i = 0; i < 2; ++i) {
    int jj = i * 256 + tid;
    int row = jj >> 3;
    int cc = (jj & 7) ^ (row & 7);
    gload16(kg0 + (size_t)kt * 4096 + row * 64 + cc * 8, Kb + (i * 256 + w * 64) * 8);
    gload16(vg0 + (size_t)row * S_LEN + kt * 64 + cc * 8, Vb + (i * 256 + w * 64) * 8);
  }
}

__global__ __launch_bounds__(256) void attn_mfma(const unsigned short* __restrict__ qp_,
                                                 const unsigned short* __restrict__ kp_,
                                                 const unsigned short* __restrict__ vtp_,
                                                 unsigned short* __restrict__ yb) {
  __shared__ __align__(16) unsigned short Kl[2][4096];
  __shared__ __align__(16) unsigned short Vl[2][4096];
  const int tid = threadIdx.x;
  const int lane = tid & 63, w = tid >> 6;
  const int l15 = lane & 15, l4 = lane >> 4;
  // XCD grouping: all 16 blocks of a bh land on XCD bh%8 (round-robin dispatch)
  const int j = blockIdx.x;
  const int bh = (j & 7) + 8 * (j >> 7);
  const int pair = (j >> 3) & 15;
  const int b = bh >> 4, h = bh & 15;

  const unsigned short* kg0 = kp_ + (size_t)bh * S_LEN * 64;
  const unsigned short* vg0 = vtp_ + (size_t)bh * 64 * S_LEN;

  for (int pass = 0; pass < 2; ++pass) {
    const int qt = pass ? pair : 31 - pair;    // big tile first
    const unsigned short* qp = qp_ + ((size_t)bh * S_LEN + qt * 64 + w * 16 + l15) * 64;
    short8v qf[2];
#pragma unroll
    for (int c2 = 0; c2 < 2; ++c2) {
      union { short4v h[2]; short8v v; } u;
      u.h[0] = *(const short4v*)(qp + c2 * 32 + 4 * l4);
      u.h[1] = *(const short4v*)(qp + c2 * 32 + 16 + 4 * l4);
      qf[c2] = u.v;
    }
    floatx4 o[4] = {};
    float mrun = -1e30f, lsum = 0.f;

    stage_tiles(kg0, vg0, 0, Kl[0], Vl[0], tid, w);   // prologue

    for (int kt = 0; kt <= qt; ++kt) {
      const int cur = kt & 1;
      if (kt < qt) {
        stage_tiles(kg0, vg0, kt + 1, Kl[cur ^ 1], Vl[cur ^ 1], tid, w);
        asm volatile("s_waitcnt vmcnt(4)" ::: "memory");   // current tile's 4 loads done
      } else {
        asm volatile("s_waitcnt vmcnt(0)" ::: "memory");
      }
      __syncthreads();

      const unsigned short* Kc = Kl[cur];
      const unsigned short* Vc = Vl[cur];
      const bool diag = (kt == qt);
      float s_[4][4];
      __builtin_amdgcn_s_setprio(1);
#pragma unroll
      for (int g = 0; g < 4; ++g) {
        if (diag && g > w) {
          s_[g][0] = s_[g][1] = s_[g][2] = s_[g][3] = -INFINITY;
          continue;
        }
        short8v k0 = readfrag(Kc, g * 16 + l15, 0, l4);
        short8v k1 = readfrag(Kc, g * 16 + l15, 1, l4);
        floatx4 t = {0.f, 0.f, 0.f, 0.f};
        t = __builtin_amdgcn_mfma_f32_16x16x32_bf16(k0, qf[0], t, 0, 0, 0);
        t = __builtin_amdgcn_mfma_f32_16x16x32_bf16(k1, qf[1], t, 0, 0, 0);
#pragma unroll
        for (int r = 0; r < 4; ++r) {
          float v = t[r];
          if (diag && g == w && (l4 * 4 + r > l15)) v = -INFINITY;
          s_[g][r] = v;
        }
      }
      __builtin_amdgcn_s_setprio(0);

      // row max (q-row = l15, replicated over l4 after xor-reduce)
      float tm = -INFINITY;
#pragma unroll
      for (int g = 0; g < 4; ++g)
#pragma unroll
        for (int r = 0; r < 4; ++r) tm = fmaxf(tm, s_[g][r]);
      tm = fmaxf(tm, __shfl_xor(tm, 16));
      tm = fmaxf(tm, __shfl_xor(tm, 32));

      // defer-max: skip rescale if no row grew by more than 3 (log2 units; p<=8)
      if (!__all(tm <= mrun + 3.0f)) {
        float nm = fmaxf(mrun, tm);
        float rs = exp2f(mrun - nm);
        mrun = nm;
        lsum *= rs;
        float rsr[4];
#pragma unroll
        for (int r = 0; r < 4; ++r) rsr[r] = __shfl(rs, l4 * 4 + r);
#pragma unroll
        for (int dt = 0; dt < 4; ++dt)
#pragma unroll
          for (int r = 0; r < 4; ++r) o[dt][r] *= rsr[r];
      }

      union { unsigned short u[16]; short8v v[2]; } pk;
      float psum = 0.f;
#pragma unroll
      for (int g = 0; g < 4; ++g)
#pragma unroll
        for (int r = 0; r < 4; ++r) {
          float p = exp2f(s_[g][r] - mrun);
          psum += p;
          pk.u[g * 4 + r] = f2bf(p);
        }
      lsum += psum;

      __builtin_amdgcn_s_setprio(1);
#pragma unroll
      for (int dt = 0; dt < 4; ++dt) {
        short8v v0 = readfrag(Vc, dt * 16 + l15, 0, l4);
        short8v v1 = readfrag(Vc, dt * 16 + l15, 1, l4);
        o[dt] = __builtin_amdgcn_mfma_f32_16x16x32_bf16(pk.v[0], v0, o[dt], 0, 0, 0);
        o[dt] = __builtin_amdgcn_mfma_f32_16x16x32_bf16(pk.v[1], v1, o[dt], 0, 0, 0);
      }
      __builtin_amdgcn_s_setprio(0);
      __syncthreads();
    }

    lsum += __shfl_xor(lsum, 16);
    lsum += __shfl_xor(lsum, 32);
    float linv = 1.f / lsum;
    float lr[4];
#pragma unroll
    for (int r = 0; r < 4; ++r) lr[r] = __shfl(linv, l4 * 4 + r);
    // yb store, k-permuted columns for GEMM2's A operand
#pragma unroll
    for (int dt = 0; dt < 4; ++dt)
#pragma unroll
      for (int r = 0; r < 4; ++r) {
        size_t row = (size_t)(b * S_LEN + qt * 64 + w * 16 + l4 * 4 + r);
        int col = (h * 2 + (dt >> 1)) * 32 + (l15 >> 2) * 8 + (l15 & 3) + 4 * (dt & 1);
        yb[row * DMODEL + col] = f2bf(o[dt][r] * lr[r]);
      }
  }
}

// ---------------- launch ----------------
extern "C" void kernel_launch(void* const* d_in, const int* in_sizes, int n_in,
                              void* d_out, int out_size, void* d_ws, size_t ws_size,
                              hipStream_t stream) {
  const float* x     = (const float*)d_in[0];
  const float* wqkv  = (const float*)d_in[1];
  const float* w_out = (const float*)d_in[2];
  const float* cosp  = (const float*)d_in[3];
  const float* sinp  = (const float*)d_in[4];
  const int*   tpos  = (const int*)d_in[5];
  float* out = (float*)d_out;
  char* ws = (char*)d_ws;

  const size_t MB = 1024 * 1024;
  unsigned short* xb    = (unsigned short*)(ws + 0);        // 8 MB
  unsigned short* wqkvb = (unsigned short*)(ws + 8 * MB);   // 6 MB
  unsigned short* wob   = (unsigned short*)(ws + 14 * MB);  // 2 MB
  unsigned short* qkvb  = (unsigned short*)(ws + 16 * MB);  // 24 MB
  unsigned short* qpk   = (unsigned short*)(ws + 40 * MB);  // 8 MB
  unsigned short* kpk   = (unsigned short*)(ws + 48 * MB);  // 8 MB
  unsigned short* vtpk  = (unsigned short*)(ws + 56 * MB);  // 8 MB
  unsigned short* yb    = (unsigned short*)(ws + 0);        // 8 MB (reuse xb)

  cast_bf16_perm_k<<<2048, 256, 0, stream>>>(x, xb, 524288);
  cast_bf16_perm_k<<<1536, 256, 0, stream>>>(wqkv, wqkvb, 393216);
  cast_bf16_perm_k<<<512, 256, 0, stream>>>(w_out, wob, 131072);

  gemm_bt<true><<<dim3(24, 32), 256, 0, stream>>>(xb, wqkvb, qkvb, 4096, QKVN, 1024);

  rope_pack_k<<<1024, 256, 0, stream>>>(qkvb, qpk, kpk, vtpk, cosp, sinp, tpos);

  attn_mfma<<<512, 256, 0, stream>>>(qpk, kpk, vtpk, yb);

  gemm_bt<false><<<dim3(8, 32), 256, 0, stream>>>(yb, wob, out, 4096, DMODEL, 1024);
}

// Round 7
// 205.558 us; speedup vs baseline: 7.6281x; 1.0790x over previous
//
#include <hip/hip_runtime.h>
#include <hip/hip_bf16.h>

// CausalMultiHeadSelfAttention  B=2 S=2048 D_MODEL=1024 H=16 DH=64
// Pipeline: cast->bf16 (k-permuted) | GEMM1 (slot-swizzled LDS) | rope+pack
// (Q pre-scaled, Q/K/vT chunk-permuted) | MFMA flash attn (1024 blocks,
// XCD-grouped, double-buffered, b128 frags) | GEMM2
//
// chunk permutation: stored 16B chunk c of a 32-elem k-block = logical
// {4c..4c+3, 16+4c..16+4c+3} -> MFMA A/B fragment for lane-group l4 is one
// contiguous 16B = one ds_read_b128.

#define S_LEN 2048
#define DMODEL 1024
#define NH 16
#define QKVN 3072

typedef __attribute__((ext_vector_type(4))) short short4v;
typedef __attribute__((ext_vector_type(8))) short short8v;
typedef __attribute__((ext_vector_type(4))) float floatx4;

#define CSOFT 0.18033688f   // 0.125 * log2(e): folded into Q at pack time

__device__ __forceinline__ unsigned short f2bf(float f) {
  unsigned int u = __float_as_uint(f);
  u += 0x7FFFu + ((u >> 16) & 1u);
  return (unsigned short)(u >> 16);
}
__device__ __forceinline__ float bf2f(unsigned short u) {
  return __uint_as_float(((unsigned int)u) << 16);
}
__device__ __forceinline__ void gload16(const void* g, void* l) {
  __builtin_amdgcn_global_load_lds((const __attribute__((address_space(1))) void*)g,
                                   (__attribute__((address_space(3))) void*)l,
                                   16, 0, 0);
}
// ushort4-group c (4 logical elems) -> offset within 64-elem span, permuted
__device__ __forceinline__ int perm4(int c) {
  return (c >> 3) * 32 + (c & 3) * 8 + ((c >> 2) & 1) * 4;
}

// ---------------- fp32 -> bf16 cast with k-block permutation ----------------
__global__ __launch_bounds__(256) void cast_bf16_perm_k(const float* __restrict__ in,
                                                        unsigned short* __restrict__ out,
                                                        int nchunk) {
  int i = blockIdx.x * 256 + threadIdx.x;
  if (i >= nchunk) return;
  int c = i & 3;
  const float4* f4 = reinterpret_cast<const float4*>(in);
  float4 lo = f4[(i >> 2) * 8 + c];
  float4 hi = f4[(i >> 2) * 8 + 4 + c];
  short8v o;
  o[0] = (short)f2bf(lo.x); o[1] = (short)f2bf(lo.y);
  o[2] = (short)f2bf(lo.z); o[3] = (short)f2bf(lo.w);
  o[4] = (short)f2bf(hi.x); o[5] = (short)f2bf(hi.y);
  o[6] = (short)f2bf(hi.z); o[7] = (short)f2bf(hi.w);
  reinterpret_cast<short8v*>(out)[i] = o;
}

// ---------------- bf16 MFMA GEMM: C[M,N] = A[M,K]*B[N,K]^T (A,B k-permuted) ----------------
// LDS slot swizzle: chunk c of LDS-row r stored at slot (c + (r>>1))&3.
template <bool OUT_BF16>
__global__ __launch_bounds__(256) void gemm_bt(const unsigned short* __restrict__ A,
                                               const unsigned short* __restrict__ Bm,
                                               void* __restrict__ Cp, int M, int N, int K) {
  __shared__ __align__(16) unsigned short As[128 * 32];
  __shared__ __align__(16) unsigned short Bs[128 * 32];
  const int tid = threadIdx.x;
  const int lane = tid & 63;
  const int w = tid >> 6;
  const int wm = w >> 1, wn = w & 1;
  const int l15 = lane & 15, l4 = lane >> 4;
  const int bm = blockIdx.y * 128, bn = blockIdx.x * 128;
  const int srow = lane >> 2;
  // dest slot = lane&3 must hold logical chunk (slot - (r>>1))&3
  const int schunk = ((lane & 3) - ((lane >> 3) & 3)) & 3;
  const int rslot = (l4 + (l15 >> 1)) & 3;   // read slot, constant per lane

  floatx4 acc[4][4] = {};

  for (int k0 = 0; k0 < K; k0 += 32) {
#pragma unroll
    for (int j = 0; j < 2; ++j) {
      const unsigned short* ga = A + (size_t)(bm + j * 64 + w * 16 + srow) * K + k0 + schunk * 8;
      gload16(ga, &As[j * 2048 + w * 512]);
      const unsigned short* gb = Bm + (size_t)(bn + j * 64 + w * 16 + srow) * K + k0 + schunk * 8;
      gload16(gb, &Bs[j * 2048 + w * 512]);
    }
    asm volatile("s_waitcnt vmcnt(0)" ::: "memory");
    __syncthreads();

    short8v af[4], bfr[4];
#pragma unroll
    for (int f = 0; f < 4; ++f) {
      af[f]  = *(const short8v*)(As + (wm * 64 + f * 16 + l15) * 32 + rslot * 8);
      bfr[f] = *(const short8v*)(Bs + (wn * 64 + f * 16 + l15) * 32 + rslot * 8);
    }
#pragma unroll
    for (int f = 0; f < 4; ++f)
#pragma unroll
      for (int g = 0; g < 4; ++g)
        acc[f][g] = __builtin_amdgcn_mfma_f32_16x16x32_bf16(af[f], bfr[g], acc[f][g], 0, 0, 0);
    __syncthreads();
  }

#pragma unroll
  for (int f = 0; f < 4; ++f)
#pragma unroll
    for (int g = 0; g < 4; ++g)
#pragma unroll
      for (int r = 0; r < 4; ++r) {
        int row = bm + wm * 64 + f * 16 + l4 * 4 + r;
        int col = bn + wn * 64 + g * 16 + l15;
        if (OUT_BF16)
          ((unsigned short*)Cp)[(size_t)row * N + col] = f2bf(acc[f][g][r]);
        else
          ((float*)Cp)[(size_t)row * N + col] = acc[f][g][r];
      }
}

// ---------------- rope + pack ----------------
// Q pre-scaled by CSOFT; Q/K/vT written with chunk permutation (perm4).
__global__ __launch_bounds__(256) void rope_pack_k(const unsigned short* __restrict__ qkvb,
                                                   unsigned short* __restrict__ qp_,
                                                   unsigned short* __restrict__ kp_,
                                                   unsigned short* __restrict__ vtp_,
                                                   const float* __restrict__ cosp,
                                                   const float* __restrict__ sinp,
                                                   const int* __restrict__ tpos) {
  __shared__ unsigned short Vs[64][68];
  const int tid = threadIdx.x;
  const int bh = blockIdx.x >> 5;
  const int st = blockIdx.x & 31;
  const int b = bh >> 4, h = bh & 15;
  const int c = tid & 15, t0 = tid >> 4;
  const int s0 = st * 64;
  const int pc = perm4(c);

#pragma unroll
  for (int it = 0; it < 4; ++it) {
    const int tl = it * 16 + t0;
    const int s = s0 + tl;
    const int tp = tpos[s];
    const size_t base = ((size_t)(b * S_LEN + s)) * QKVN + h * 64 + c * 4;
    const float co0 = cosp[tp * 32 + 2 * c], si0 = sinp[tp * 32 + 2 * c];
    const float co1 = cosp[tp * 32 + 2 * c + 1], si1 = sinp[tp * 32 + 2 * c + 1];
    // Q (scaled), permuted store
    {
      const float c0 = co0 * CSOFT, s0q = si0 * CSOFT;
      const float c1 = co1 * CSOFT, s1q = si1 * CSOFT;
      ushort4 rv = *(const ushort4*)(qkvb + base);
      float a0 = bf2f(rv.x), a1 = bf2f(rv.y), a2 = bf2f(rv.z), a3 = bf2f(rv.w);
      ushort4 ov;
      ov.x = f2bf(a0 * c0 - a1 * s0q); ov.y = f2bf(a0 * s0q + a1 * c0);
      ov.z = f2bf(a2 * c1 - a3 * s1q); ov.w = f2bf(a2 * s1q + a3 * c1);
      *(ushort4*)(qp_ + ((size_t)bh * S_LEN + s) * 64 + pc) = ov;
    }
    // K, permuted store
    {
      ushort4 rv = *(const ushort4*)(qkvb + base + DMODEL);
      float a0 = bf2f(rv.x), a1 = bf2f(rv.y), a2 = bf2f(rv.z), a3 = bf2f(rv.w);
      ushort4 ov;
      ov.x = f2bf(a0 * co0 - a1 * si0); ov.y = f2bf(a0 * si0 + a1 * co0);
      ov.z = f2bf(a2 * co1 - a3 * si1); ov.w = f2bf(a2 * si1 + a3 * co1);
      *(ushort4*)(kp_ + ((size_t)bh * S_LEN + s) * 64 + pc) = ov;
    }
    // V -> LDS
    {
      ushort4 rv = *(const ushort4*)(qkvb + base + 2 * DMODEL);
      *(ushort4*)(&Vs[tl][c * 4]) = rv;
    }
  }
  __syncthreads();
  // vT: row d, s-group c -> permuted offset within the 64-s tile
#pragma unroll
  for (int it = 0; it < 4; ++it) {
    const int d = it * 16 + t0;
    ushort4 ov;
    ov.x = Vs[c * 4 + 0][d]; ov.y = Vs[c * 4 + 1][d];
    ov.z = Vs[c * 4 + 2][d]; ov.w = Vs[c * 4 + 3][d];
    *(ushort4*)(vtp_ + ((size_t)bh * 64 + d) * S_LEN + s0 + pc) = ov;
  }
}

// ---------------- MFMA flash attention ----------------
// LDS tile [64][64] bf16 (128B rows); stored chunk cc at slot cc^(row&7).
__device__ __forceinline__ short8v readfrag128(const unsigned short* L, int row, int cc) {
  return *(const short8v*)(L + row * 64 + (((cc) ^ (row & 7)) << 3));
}

__device__ __forceinline__ void stage_tiles(const unsigned short* kg0, const unsigned short* vg0,
                                            int kt, unsigned short* Kb, unsigned short* Vb,
                                            int tid, int w) {
#pragma unroll
  for (int i = 0; i < 2; ++i) {
    int jj = i * 256 + tid;
    int row = jj >> 3;
    int cc = (jj & 7) ^ (row & 7);
    gload16(kg0 + (size_t)kt * 4096 + row * 64 + cc * 8, Kb + (i * 256 + w * 64) * 8);
    gload16(vg0 + (size_t)row * S_LEN + kt * 64 + cc * 8, Vb + (i * 256 + w * 64) * 8);
  }
}

__global__ __launch_bounds__(256) void attn_mfma(const unsigned short* __restrict__ qp_,
                                                 const unsigned short* __restrict__ kp_,
                                                 const unsigned short* __restrict__ vtp_,
                                                 unsigned short* __restrict__ yb) {
  __shared__ __align__(16) unsigned short Kl[2][4096];
  __shared__ __align__(16) unsigned short Vl[2][4096];
  const int tid = threadIdx.x;
  const int lane = tid & 63, w = tid >> 6;
  const int l15 = lane & 15, l4 = lane >> 4;
  // 1024 blocks: XCD j&7 gets bh in {x, x+8, x+16, x+24}; big q-tiles first
  const int j = blockIdx.x;
  const int bh = (j & 7) + 8 * ((j >> 3) & 3);
  const int qt = 31 - (j >> 5);
  const int b = bh >> 4, h = bh & 15;

  const unsigned short* kg0 = kp_ + (size_t)bh * S_LEN * 64;
  const unsigned short* vg0 = vtp_ + (size_t)bh * 64 * S_LEN;

  // Q fragments (registers), chunk-permuted global: one 16B load per block
  const unsigned short* qp = qp_ + ((size_t)bh * S_LEN + qt * 64 + w * 16 + l15) * 64;
  short8v qf[2];
#pragma unroll
  for (int c2 = 0; c2 < 2; ++c2)
    qf[c2] = *(const short8v*)(qp + c2 * 32 + l4 * 8);

  floatx4 o[4] = {};
  float mrun = -1e30f, lsum = 0.f;

  stage_tiles(kg0, vg0, 0, Kl[0], Vl[0], tid, w);   // prologue

  for (int kt = 0; kt <= qt; ++kt) {
    const int cur = kt & 1;
    if (kt < qt) {
      stage_tiles(kg0, vg0, kt + 1, Kl[cur ^ 1], Vl[cur ^ 1], tid, w);
      asm volatile("s_waitcnt vmcnt(4)" ::: "memory");   // current tile's 4 loads done
    } else {
      asm volatile("s_waitcnt vmcnt(0)" ::: "memory");
    }
    __syncthreads();

    const unsigned short* Kc = Kl[cur];
    const unsigned short* Vc = Vl[cur];
    const bool diag = (kt == qt);
    float s_[4][4];
    __builtin_amdgcn_s_setprio(1);
#pragma unroll
    for (int g = 0; g < 4; ++g) {
      if (diag && g > w) {
        s_[g][0] = s_[g][1] = s_[g][2] = s_[g][3] = -INFINITY;
        continue;
      }
      short8v k0 = readfrag128(Kc, g * 16 + l15, l4);
      short8v k1 = readfrag128(Kc, g * 16 + l15, 4 + l4);
      floatx4 t = {0.f, 0.f, 0.f, 0.f};
      t = __builtin_amdgcn_mfma_f32_16x16x32_bf16(k0, qf[0], t, 0, 0, 0);
      t = __builtin_amdgcn_mfma_f32_16x16x32_bf16(k1, qf[1], t, 0, 0, 0);
#pragma unroll
      for (int r = 0; r < 4; ++r) {
        float v = t[r];
        if (diag && g == w && (l4 * 4 + r > l15)) v = -INFINITY;
        s_[g][r] = v;
      }
    }
    __builtin_amdgcn_s_setprio(0);

    // row max (q-row = l15, replicated over l4 after xor-reduce)
    float tm = -INFINITY;
#pragma unroll
    for (int g = 0; g < 4; ++g)
#pragma unroll
      for (int r = 0; r < 4; ++r) tm = fmaxf(tm, s_[g][r]);
    tm = fmaxf(tm, __shfl_xor(tm, 16));
    tm = fmaxf(tm, __shfl_xor(tm, 32));

    // defer-max: skip rescale if no row grew by more than 3 (log2 units)
    if (!__all(tm <= mrun + 3.0f)) {
      float nm = fmaxf(mrun, tm);
      float rs = exp2f(mrun - nm);
      mrun = nm;
      lsum *= rs;
      float rsr[4];
#pragma unroll
      for (int r = 0; r < 4; ++r) rsr[r] = __shfl(rs, l4 * 4 + r);
#pragma unroll
      for (int dt = 0; dt < 4; ++dt)
#pragma unroll
        for (int r = 0; r < 4; ++r) o[dt][r] *= rsr[r];
    }

    union { unsigned short u[16]; short8v v[2]; } pk;
    float psum = 0.f;
#pragma unroll
    for (int g = 0; g < 4; ++g)
#pragma unroll
      for (int r = 0; r < 4; ++r) {
        float p = exp2f(s_[g][r] - mrun);
        psum += p;
        pk.u[g * 4 + r] = f2bf(p);
      }
    lsum += psum;

    __builtin_amdgcn_s_setprio(1);
#pragma unroll
    for (int dt = 0; dt < 4; ++dt) {
      short8v v0 = readfrag128(Vc, dt * 16 + l15, l4);
      short8v v1 = readfrag128(Vc, dt * 16 + l15, 4 + l4);
      o[dt] = __builtin_amdgcn_mfma_f32_16x16x32_bf16(pk.v[0], v0, o[dt], 0, 0, 0);
      o[dt] = __builtin_amdgcn_mfma_f32_16x16x32_bf16(pk.v[1], v1, o[dt], 0, 0, 0);
    }
    __builtin_amdgcn_s_setprio(0);
    __syncthreads();
  }

  lsum += __shfl_xor(lsum, 16);
  lsum += __shfl_xor(lsum, 32);
  float linv = 1.f / lsum;
  float lr[4];
#pragma unroll
  for (int r = 0; r < 4; ++r) lr[r] = __shfl(linv, l4 * 4 + r);
  // yb store, k-permuted columns for GEMM2's A operand
#pragma unroll
  for (int dt = 0; dt < 4; ++dt)
#pragma unroll
    for (int r = 0; r < 4; ++r) {
      size_t row = (size_t)(b * S_LEN + qt * 64 + w * 16 + l4 * 4 + r);
      int col = (h * 2 + (dt >> 1)) * 32 + (l15 >> 2) * 8 + (l15 & 3) + 4 * (dt & 1);
      yb[row * DMODEL + col] = f2bf(o[dt][r] * lr[r]);
    }
}

// ---------------- launch ----------------
extern "C" void kernel_launch(void* const* d_in, const int* in_sizes, int n_in,
                              void* d_out, int out_size, void* d_ws, size_t ws_size,
                              hipStream_t stream) {
  const float* x     = (const float*)d_in[0];
  const float* wqkv  = (const float*)d_in[1];
  const float* w_out = (const float*)d_in[2];
  const float* cosp  = (const float*)d_in[3];
  const float* sinp  = (const float*)d_in[4];
  const int*   tpos  = (const int*)d_in[5];
  float* out = (float*)d_out;
  char* ws = (char*)d_ws;

  const size_t MB = 1024 * 1024;
  unsigned short* xb    = (unsigned short*)(ws + 0);        // 8 MB
  unsigned short* wqkvb = (unsigned short*)(ws + 8 * MB);   // 6 MB
  unsigned short* wob   = (unsigned short*)(ws + 14 * MB);  // 2 MB
  unsigned short* qkvb  = (unsigned short*)(ws + 16 * MB);  // 24 MB
  unsigned short* qpk   = (unsigned short*)(ws + 40 * MB);  // 8 MB
  unsigned short* kpk   = (unsigned short*)(ws + 48 * MB);  // 8 MB
  unsigned short* vtpk  = (unsigned short*)(ws + 56 * MB);  // 8 MB
  unsigned short* yb    = (unsigned short*)(ws + 0);        // 8 MB (reuse xb)

  cast_bf16_perm_k<<<2048, 256, 0, stream>>>(x, xb, 524288);
  cast_bf16_perm_k<<<1536, 256, 0, stream>>>(wqkv, wqkvb, 393216);
  cast_bf16_perm_k<<<512, 256, 0, stream>>>(w_out, wob, 131072);

  gemm_bt<true><<<dim3(24, 32), 256, 0, stream>>>(xb, wqkvb, qkvb, 4096, QKVN, 1024);

  rope_pack_k<<<1024, 256, 0, stream>>>(qkvb, qpk, kpk, vtpk, cosp, sinp, tpos);

  attn_mfma<<<1024, 256, 0, stream>>>(qpk, kpk, vtpk, yb);

  gemm_bt<false><<<dim3(8, 32), 256, 0, stream>>>(yb, wob, out, 4096, DMODEL, 1024);
}

// Round 8
// 197.509 us; speedup vs baseline: 7.9390x; 1.0408x over previous
//
#include <hip/hip_runtime.h>
#include <hip/hip_bf16.h>

// CausalMultiHeadSelfAttention  B=2 S=2048 D_MODEL=1024 H=16 DH=64
// Pipeline: cast->bf16 (k-permuted) | GEMM1 (2-phase dbuf) | rope+pack |
//           MFMA flash attn (trunc P-pack) | GEMM2 (2-phase dbuf)

#define S_LEN 2048
#define DMODEL 1024
#define NH 16
#define QKVN 3072

typedef __attribute__((ext_vector_type(4))) short short4v;
typedef __attribute__((ext_vector_type(8))) short short8v;
typedef __attribute__((ext_vector_type(4))) float floatx4;

#define CSOFT 0.18033688f   // 0.125 * log2(e): folded into Q at pack time

__device__ __forceinline__ unsigned short f2bf(float f) {
  unsigned int u = __float_as_uint(f);
  u += 0x7FFFu + ((u >> 16) & 1u);
  return (unsigned short)(u >> 16);
}
__device__ __forceinline__ float bf2f(unsigned short u) {
  return __uint_as_float(((unsigned int)u) << 16);
}
__device__ __forceinline__ void gload16(const void* g, void* l) {
  __builtin_amdgcn_global_load_lds((const __attribute__((address_space(1))) void*)g,
                                   (__attribute__((address_space(3))) void*)l,
                                   16, 0, 0);
}
// ushort4-group c (4 logical elems) -> offset within 64-elem span, permuted
__device__ __forceinline__ int perm4(int c) {
  return (c >> 3) * 32 + (c & 3) * 8 + ((c >> 2) & 1) * 4;
}

// ---------------- fp32 -> bf16 cast with k-block permutation ----------------
__global__ __launch_bounds__(256) void cast_bf16_perm_k(const float* __restrict__ in,
                                                        unsigned short* __restrict__ out,
                                                        int nchunk) {
  int i = blockIdx.x * 256 + threadIdx.x;
  if (i >= nchunk) return;
  int c = i & 3;
  const float4* f4 = reinterpret_cast<const float4*>(in);
  float4 lo = f4[(i >> 2) * 8 + c];
  float4 hi = f4[(i >> 2) * 8 + 4 + c];
  short8v o;
  o[0] = (short)f2bf(lo.x); o[1] = (short)f2bf(lo.y);
  o[2] = (short)f2bf(lo.z); o[3] = (short)f2bf(lo.w);
  o[4] = (short)f2bf(hi.x); o[5] = (short)f2bf(hi.y);
  o[6] = (short)f2bf(hi.z); o[7] = (short)f2bf(hi.w);
  reinterpret_cast<short8v*>(out)[i] = o;
}

// ---------------- bf16 MFMA GEMM: C[M,N] = A[M,K]*B[N,K]^T (A,B k-permuted) ----------------
// 2-phase: double-buffered LDS, stage(t+1) issued before compute(t), vmcnt(4).
// LDS slot swizzle: chunk c of LDS-row r stored at slot (c + (r>>1))&3.
template <bool OUT_BF16>
__global__ __launch_bounds__(256) void gemm_bt(const unsigned short* __restrict__ A,
                                               const unsigned short* __restrict__ Bm,
                                               void* __restrict__ Cp, int M, int N, int K) {
  __shared__ __align__(16) unsigned short As[2][128 * 32];
  __shared__ __align__(16) unsigned short Bs[2][128 * 32];
  const int tid = threadIdx.x;
  const int lane = tid & 63;
  const int w = tid >> 6;
  const int wm = w >> 1, wn = w & 1;
  const int l15 = lane & 15, l4 = lane >> 4;
  const int bm = blockIdx.y * 128, bn = blockIdx.x * 128;
  const int srow = lane >> 2;
  // dest slot = lane&3 must hold logical chunk (slot - (r>>1))&3
  const int schunk = ((lane & 3) - ((lane >> 3) & 3)) & 3;
  const int rslot = (l4 + (l15 >> 1)) & 3;   // read slot, constant per lane

  floatx4 acc[4][4] = {};
  const int nt = K >> 5;

#define GSTAGE(T, BUF)                                                                   \
  {                                                                                      \
    const int k0s = (T) << 5;                                                            \
    _Pragma("unroll") for (int j = 0; j < 2; ++j) {                                      \
      const unsigned short* ga =                                                         \
          A + (size_t)(bm + j * 64 + w * 16 + srow) * K + k0s + schunk * 8;              \
      gload16(ga, &As[BUF][j * 2048 + w * 512]);                                         \
      const unsigned short* gb =                                                         \
          Bm + (size_t)(bn + j * 64 + w * 16 + srow) * K + k0s + schunk * 8;             \
      gload16(gb, &Bs[BUF][j * 2048 + w * 512]);                                         \
    }                                                                                    \
  }

  GSTAGE(0, 0);
  for (int t = 0; t < nt; ++t) {
    const int cur = t & 1;
    if (t + 1 < nt) {
      GSTAGE(t + 1, cur ^ 1);
      asm volatile("s_waitcnt vmcnt(4)" ::: "memory");   // tile t's 4 loads landed
    } else {
      asm volatile("s_waitcnt vmcnt(0)" ::: "memory");
    }
    __syncthreads();

    short8v af[4], bfr[4];
#pragma unroll
    for (int f = 0; f < 4; ++f) {
      af[f]  = *(const short8v*)(&As[cur][(wm * 64 + f * 16 + l15) * 32 + rslot * 8]);
      bfr[f] = *(const short8v*)(&Bs[cur][(wn * 64 + f * 16 + l15) * 32 + rslot * 8]);
    }
#pragma unroll
    for (int f = 0; f < 4; ++f)
#pragma unroll
      for (int g = 0; g < 4; ++g)
        acc[f][g] = __builtin_amdgcn_mfma_f32_16x16x32_bf16(af[f], bfr[g], acc[f][g], 0, 0, 0);
    __syncthreads();
  }
#undef GSTAGE

#pragma unroll
  for (int f = 0; f < 4; ++f)
#pragma unroll
    for (int g = 0; g < 4; ++g)
#pragma unroll
      for (int r = 0; r < 4; ++r) {
        int row = bm + wm * 64 + f * 16 + l4 * 4 + r;
        int col = bn + wn * 64 + g * 16 + l15;
        if (OUT_BF16)
          ((unsigned short*)Cp)[(size_t)row * N + col] = f2bf(acc[f][g][r]);
        else
          ((float*)Cp)[(size_t)row * N + col] = acc[f][g][r];
      }
}

// ---------------- rope + pack ----------------
// Q pre-scaled by CSOFT; Q/K/vT written with chunk permutation (perm4).
__global__ __launch_bounds__(256) void rope_pack_k(const unsigned short* __restrict__ qkvb,
                                                   unsigned short* __restrict__ qp_,
                                                   unsigned short* __restrict__ kp_,
                                                   unsigned short* __restrict__ vtp_,
                                                   const float* __restrict__ cosp,
                                                   const float* __restrict__ sinp,
                                                   const int* __restrict__ tpos) {
  __shared__ unsigned short Vs[64][68];
  const int tid = threadIdx.x;
  const int bh = blockIdx.x >> 5;
  const int st = blockIdx.x & 31;
  const int b = bh >> 4, h = bh & 15;
  const int c = tid & 15, t0 = tid >> 4;
  const int s0 = st * 64;
  const int pc = perm4(c);

#pragma unroll
  for (int it = 0; it < 4; ++it) {
    const int tl = it * 16 + t0;
    const int s = s0 + tl;
    const int tp = tpos[s];
    const size_t base = ((size_t)(b * S_LEN + s)) * QKVN + h * 64 + c * 4;
    const float co0 = cosp[tp * 32 + 2 * c], si0 = sinp[tp * 32 + 2 * c];
    const float co1 = cosp[tp * 32 + 2 * c + 1], si1 = sinp[tp * 32 + 2 * c + 1];
    // Q (scaled), permuted store
    {
      const float c0 = co0 * CSOFT, s0q = si0 * CSOFT;
      const float c1 = co1 * CSOFT, s1q = si1 * CSOFT;
      ushort4 rv = *(const ushort4*)(qkvb + base);
      float a0 = bf2f(rv.x), a1 = bf2f(rv.y), a2 = bf2f(rv.z), a3 = bf2f(rv.w);
      ushort4 ov;
      ov.x = f2bf(a0 * c0 - a1 * s0q); ov.y = f2bf(a0 * s0q + a1 * c0);
      ov.z = f2bf(a2 * c1 - a3 * s1q); ov.w = f2bf(a2 * s1q + a3 * c1);
      *(ushort4*)(qp_ + ((size_t)bh * S_LEN + s) * 64 + pc) = ov;
    }
    // K, permuted store
    {
      ushort4 rv = *(const ushort4*)(qkvb + base + DMODEL);
      float a0 = bf2f(rv.x), a1 = bf2f(rv.y), a2 = bf2f(rv.z), a3 = bf2f(rv.w);
      ushort4 ov;
      ov.x = f2bf(a0 * co0 - a1 * si0); ov.y = f2bf(a0 * si0 + a1 * co0);
      ov.z = f2bf(a2 * co1 - a3 * si1); ov.w = f2bf(a2 * si1 + a3 * co1);
      *(ushort4*)(kp_ + ((size_t)bh * S_LEN + s) * 64 + pc) = ov;
    }
    // V -> LDS
    {
      ushort4 rv = *(const ushort4*)(qkvb + base + 2 * DMODEL);
      *(ushort4*)(&Vs[tl][c * 4]) = rv;
    }
  }
  __syncthreads();
  // vT: row d, s-group c -> permuted offset within the 64-s tile
#pragma unroll
  for (int it = 0; it < 4; ++it) {
    const int d = it * 16 + t0;
    ushort4 ov;
    ov.x = Vs[c * 4 + 0][d]; ov.y = Vs[c * 4 + 1][d];
    ov.z = Vs[c * 4 + 2][d]; ov.w = Vs[c * 4 + 3][d];
    *(ushort4*)(vtp_ + ((size_t)bh * 64 + d) * S_LEN + s0 + pc) = ov;
  }
}

// ---------------- MFMA flash attention ----------------
// LDS tile [64][64] bf16 (128B rows); stored chunk cc at slot cc^(row&7).
__device__ __forceinline__ short8v readfrag128(const unsigned short* L, int row, int cc) {
  return *(const short8v*)(L + row * 64 + (((cc) ^ (row & 7)) << 3));
}

__device__ __forceinline__ void stage_tiles(const unsigned short* kg0, const unsigned short* vg0,
                                            int kt, unsigned short* Kb, unsigned short* Vb,
                                            int tid, int w) {
#pragma unroll
  for (int i = 0; i < 2; ++i) {
    int jj = i * 256 + tid;
    int row = jj >> 3;
    int cc = (jj & 7) ^ (row & 7);
    gload16(kg0 + (size_t)kt * 4096 + row * 64 + cc * 8, Kb + (i * 256 + w * 64) * 8);
    gload16(vg0 + (size_t)row * S_LEN + kt * 64 + cc * 8, Vb + (i * 256 + w * 64) * 8);
  }
}

__global__ __launch_bounds__(256) void attn_mfma(const unsigned short* __restrict__ qp_,
                                                 const unsigned short* __restrict__ kp_,
                                                 const unsigned short* __restrict__ vtp_,
                                                 unsigned short* __restrict__ yb) {
  __shared__ __align__(16) unsigned short Kl[2][4096];
  __shared__ __align__(16) unsigned short Vl[2][4096];
  const int tid = threadIdx.x;
  const int lane = tid & 63, w = tid >> 6;
  const int l15 = lane & 15, l4 = lane >> 4;
  // 1024 blocks: XCD j&7 gets bh in {x, x+8, x+16, x+24}; big q-tiles first
  const int j = blockIdx.x;
  const int bh = (j & 7) + 8 * ((j >> 3) & 3);
  const int qt = 31 - (j >> 5);
  const int b = bh >> 4, h = bh & 15;

  const unsigned short* kg0 = kp_ + (size_t)bh * S_LEN * 64;
  const unsigned short* vg0 = vtp_ + (size_t)bh * 64 * S_LEN;

  // Q fragments (registers), chunk-permuted global: one 16B load per block
  const unsigned short* qp = qp_ + ((size_t)bh * S_LEN + qt * 64 + w * 16 + l15) * 64;
  short8v qf[2];
#pragma unroll
  for (int c2 = 0; c2 < 2; ++c2)
    qf[c2] = *(const short8v*)(qp + c2 * 32 + l4 * 8);

  floatx4 o[4] = {};
  float mrun = -1e30f, lsum = 0.f;

  stage_tiles(kg0, vg0, 0, Kl[0], Vl[0], tid, w);   // prologue

  for (int kt = 0; kt <= qt; ++kt) {
    const int cur = kt & 1;
    if (kt < qt) {
      stage_tiles(kg0, vg0, kt + 1, Kl[cur ^ 1], Vl[cur ^ 1], tid, w);
      asm volatile("s_waitcnt vmcnt(4)" ::: "memory");   // current tile's 4 loads done
    } else {
      asm volatile("s_waitcnt vmcnt(0)" ::: "memory");
    }
    __syncthreads();

    const unsigned short* Kc = Kl[cur];
    const unsigned short* Vc = Vl[cur];
    const bool diag = (kt == qt);
    float s_[4][4];
    __builtin_amdgcn_s_setprio(1);
#pragma unroll
    for (int g = 0; g < 4; ++g) {
      if (diag && g > w) {
        s_[g][0] = s_[g][1] = s_[g][2] = s_[g][3] = -INFINITY;
        continue;
      }
      short8v k0 = readfrag128(Kc, g * 16 + l15, l4);
      short8v k1 = readfrag128(Kc, g * 16 + l15, 4 + l4);
      floatx4 t = {0.f, 0.f, 0.f, 0.f};
      t = __builtin_amdgcn_mfma_f32_16x16x32_bf16(k0, qf[0], t, 0, 0, 0);
      t = __builtin_amdgcn_mfma_f32_16x16x32_bf16(k1, qf[1], t, 0, 0, 0);
#pragma unroll
      for (int r = 0; r < 4; ++r) {
        float v = t[r];
        if (diag && g == w && (l4 * 4 + r > l15)) v = -INFINITY;
        s_[g][r] = v;
      }
    }
    __builtin_amdgcn_s_setprio(0);

    // row max (q-row = l15, replicated over l4 after xor-reduce)
    float tm = -INFINITY;
#pragma unroll
    for (int g = 0; g < 4; ++g)
#pragma unroll
      for (int r = 0; r < 4; ++r) tm = fmaxf(tm, s_[g][r]);
    tm = fmaxf(tm, __shfl_xor(tm, 16));
    tm = fmaxf(tm, __shfl_xor(tm, 32));

    // defer-max: skip rescale if no row grew by more than 3 (log2 units)
    if (!__all(tm <= mrun + 3.0f)) {
      float nm = fmaxf(mrun, tm);
      float rs = exp2f(mrun - nm);
      mrun = nm;
      lsum *= rs;
      float rsr[4];
#pragma unroll
      for (int r = 0; r < 4; ++r) rsr[r] = __shfl(rs, l4 * 4 + r);
#pragma unroll
      for (int dt = 0; dt < 4; ++dt)
#pragma unroll
        for (int r = 0; r < 4; ++r) o[dt][r] *= rsr[r];
    }

    union { unsigned short u[16]; short8v v[2]; } pk;
    float psum = 0.f;
#pragma unroll
    for (int g = 0; g < 4; ++g)
#pragma unroll
      for (int r = 0; r < 4; ++r) {
        float p = exp2f(s_[g][r] - mrun);
        psum += p;
        // truncating f32->bf16 (p in [0,8]; 1 VALU op vs 4 for RNE)
        pk.u[g * 4 + r] = (unsigned short)(__float_as_uint(p) >> 16);
      }
    lsum += psum;

    __builtin_amdgcn_s_setprio(1);
#pragma unroll
    for (int dt = 0; dt < 4; ++dt) {
      short8v v0 = readfrag128(Vc, dt * 16 + l15, l4);
      short8v v1 = readfrag128(Vc, dt * 16 + l15, 4 + l4);
      o[dt] = __builtin_amdgcn_mfma_f32_16x16x32_bf16(pk.v[0], v0, o[dt], 0, 0, 0);
      o[dt] = __builtin_amdgcn_mfma_f32_16x16x32_bf16(pk.v[1], v1, o[dt], 0, 0, 0);
    }
    __builtin_amdgcn_s_setprio(0);
    __syncthreads();
  }

  lsum += __shfl_xor(lsum, 16);
  lsum += __shfl_xor(lsum, 32);
  float linv = 1.f / lsum;
  float lr[4];
#pragma unroll
  for (int r = 0; r < 4; ++r) lr[r] = __shfl(linv, l4 * 4 + r);
  // yb store, k-permuted columns for GEMM2's A operand
#pragma unroll
  for (int dt = 0; dt < 4; ++dt)
#pragma unroll
    for (int r = 0; r < 4; ++r) {
      size_t row = (size_t)(b * S_LEN + qt * 64 + w * 16 + l4 * 4 + r);
      int col = (h * 2 + (dt >> 1)) * 32 + (l15 >> 2) * 8 + (l15 & 3) + 4 * (dt & 1);
      yb[row * DMODEL + col] = f2bf(o[dt][r] * lr[r]);
    }
}

// ---------------- launch ----------------
extern "C" void kernel_launch(void* const* d_in, const int* in_sizes, int n_in,
                              void* d_out, int out_size, void* d_ws, size_t ws_size,
                              hipStream_t stream) {
  const float* x     = (const float*)d_in[0];
  const float* wqkv  = (const float*)d_in[1];
  const float* w_out = (const float*)d_in[2];
  const float* cosp  = (const float*)d_in[3];
  const float* sinp  = (const float*)d_in[4];
  const int*   tpos  = (const int*)d_in[5];
  float* out = (float*)d_out;
  char* ws = (char*)d_ws;

  const size_t MB = 1024 * 1024;
  unsigned short* xb    = (unsigned short*)(ws + 0);        // 8 MB
  unsigned short* wqkvb = (unsigned short*)(ws + 8 * MB);   // 6 MB
  unsigned short* wob   = (unsigned short*)(ws + 14 * MB);  // 2 MB
  unsigned short* qkvb  = (unsigned short*)(ws + 16 * MB);  // 24 MB
  unsigned short* qpk   = (unsigned short*)(ws + 40 * MB);  // 8 MB
  unsigned short* kpk   = (unsigned short*)(ws + 48 * MB);  // 8 MB
  unsigned short* vtpk  = (unsigned short*)(ws + 56 * MB);  // 8 MB
  unsigned short* yb    = (unsigned short*)(ws + 0);        // 8 MB (reuse xb)

  cast_bf16_perm_k<<<2048, 256, 0, stream>>>(x, xb, 524288);
  cast_bf16_perm_k<<<1536, 256, 0, stream>>>(wqkv, wqkvb, 393216);
  cast_bf16_perm_k<<<512, 256, 0, stream>>>(w_out, wob, 131072);

  gemm_bt<true><<<dim3(24, 32), 256, 0, stream>>>(xb, wqkvb, qkvb, 4096, QKVN, 1024);

  rope_pack_k<<<1024, 256, 0, stream>>>(qkvb, qpk, kpk, vtpk, cosp, sinp, tpos);

  attn_mfma<<<1024, 256, 0, stream>>>(qpk, kpk, vtpk, yb);

  gemm_bt<false><<<dim3(8, 32), 256, 0, stream>>>(yb, wob, out, 4096, DMODEL, 1024);
}